// Round 3
// baseline (518.332 us; speedup 1.0000x reference)
//
#include <hip/hip_runtime.h>
#include <cstddef>
#include <math.h>

// Problem dims
// B=32, C=1024, T=64, D=64, F_OUT=128, S_DIM=64, N_STG=5, H_MLP=64

// workspace layout (float offsets)
#define LOGA_OFF  0u          // 1024*1024 = 1048576
#define XRED_OFF  1048576u    // 32*1024*64 = 2097152
#define XGLOB_OFF 3145728u    // 32*64 = 2048
#define Z_OFF     3147776u    // 32*1024*128 = 4194304
#define EI_OFF    7342080u    // 32768
#define EJ_OFF    7374848u    // 32768
#define EC_OFF    7407616u    // 32

// ---------------- logA = log(A + 1e-8) ----------------
__global__ __launch_bounds__(256) void k_logA(const float* __restrict__ A,
                                              float* __restrict__ out) {
  int base = blockIdx.x * 1024 + threadIdx.x;
#pragma unroll
  for (int k = 0; k < 4; ++k)
    out[base + k * 256] = logf(A[base + k * 256] + 1e-8f);
}

// ---------------- x_red = mean over T ----------------
// one block per (b,c); 64x64 tile = 1024 float4
__global__ __launch_bounds__(256) void k_xred(const float4* __restrict__ X4,
                                              float4* __restrict__ XR4) {
  __shared__ float4 part[256];
  int bc = blockIdx.x;
  int tid = threadIdx.x;
  int dq = tid & 15, tw = tid >> 4;
  const float4* base = X4 + (size_t)bc * 1024;
  float4 acc = make_float4(0.f, 0.f, 0.f, 0.f);
#pragma unroll
  for (int k = 0; k < 4; ++k) {
    float4 v = base[(tw + k * 16) * 16 + dq];
    acc.x += v.x; acc.y += v.y; acc.z += v.z; acc.w += v.w;
  }
  part[tid] = acc;
  __syncthreads();
  if (tid < 16) {
    float4 s = part[tid];
#pragma unroll
    for (int w = 1; w < 16; ++w) {
      float4 v = part[w * 16 + tid];
      s.x += v.x; s.y += v.y; s.z += v.z; s.w += v.w;
    }
    const float inv = 1.0f / 64.0f;
    s.x *= inv; s.y *= inv; s.z *= inv; s.w *= inv;
    XR4[(size_t)bc * 16 + tid] = s;
  }
}

// ---------------- x_glob = mean over C of x_red ----------------
__global__ __launch_bounds__(256) void k_xglob(const float* __restrict__ XR,
                                               float* __restrict__ XG) {
  __shared__ float part[256];
  int b = blockIdx.x, tid = threadIdx.x;
  int d = tid & 63, cq = tid >> 6;
  float acc = 0.f;
  for (int c = cq; c < 1024; c += 4)
    acc += XR[((size_t)b * 1024 + c) * 64 + d];
  part[tid] = acc;
  __syncthreads();
  if (tid < 64) {
    float s = part[tid] + part[64 + tid] + part[128 + tid] + part[192 + tid];
    XG[b * 64 + tid] = s * (1.0f / 1024.0f);
  }
}

// ---------------- Z = x_red @ W_proj^T + b_proj ----------------
// 32 rows per block; W in LDS transposed [d][f] stride 129 (conflict-free reads)
__global__ __launch_bounds__(256) void k_Z(const float4* __restrict__ XR4,
                                           const float* __restrict__ W,
                                           const float* __restrict__ bproj,
                                           float* __restrict__ Z) {
  __shared__ float Wl[64 * 129];
  __shared__ float4 xr4[32 * 16];
  int tid = threadIdx.x;
  int rb = blockIdx.x * 32;  // flat row base in [0, 32768)
#pragma unroll
  for (int k = 0; k < 32; ++k) {
    int g = k * 256 + tid;         // g = f*64 + d
    Wl[(g & 63) * 129 + (g >> 6)] = W[g];
  }
#pragma unroll
  for (int k = 0; k < 2; ++k)
    xr4[k * 256 + tid] = XR4[(size_t)rb * 16 + k * 256 + tid];
  __syncthreads();

  int f = tid & 127, rg = tid >> 7;
  float wreg[64];
#pragma unroll
  for (int d = 0; d < 64; ++d) wreg[d] = Wl[d * 129 + f];
  float bias = bproj[f];
  float acc[16];
#pragma unroll
  for (int r = 0; r < 16; ++r) acc[r] = bias;
#pragma unroll
  for (int r = 0; r < 16; ++r) {
    int row = rg * 16 + r;
#pragma unroll
    for (int dq = 0; dq < 16; ++dq) {
      float4 xv = xr4[row * 16 + dq];
      acc[r] = fmaf(wreg[dq * 4 + 0], xv.x, acc[r]);
      acc[r] = fmaf(wreg[dq * 4 + 1], xv.y, acc[r]);
      acc[r] = fmaf(wreg[dq * 4 + 2], xv.z, acc[r]);
      acc[r] = fmaf(wreg[dq * 4 + 3], xv.w, acc[r]);
    }
  }
#pragma unroll
  for (int r = 0; r < 16; ++r) {
    int row = rg * 16 + r;
    Z[((size_t)rb + row) * 128 + f] = acc[r];
  }
}

// ---------------- ei = Z@a_i, ej = Z@a_j ----------------
// one wave per row
__global__ __launch_bounds__(256) void k_e(const float* __restrict__ Z,
                                           const float* __restrict__ att,
                                           float* __restrict__ ei,
                                           float* __restrict__ ej) {
  int tid = threadIdx.x;
  int row = blockIdx.x * 4 + (tid >> 6);
  int lane = tid & 63;
  float z0 = Z[(size_t)row * 128 + lane];
  float z1 = Z[(size_t)row * 128 + 64 + lane];
  float si = z0 * att[lane] + z1 * att[64 + lane];
  float sj = z0 * att[128 + lane] + z1 * att[192 + lane];
#pragma unroll
  for (int o = 32; o; o >>= 1) {
    si += __shfl_xor(si, o);
    sj += __shfl_xor(sj, o);
  }
  if (lane == 0) { ei[row] = si; ej[row] = sj; }
}

// ---------------- s, c, e_c chain (tiny) ----------------
__global__ __launch_bounds__(64) void k_small(const float* __restrict__ XG,
    const float* __restrict__ Ws1, const float* __restrict__ bs1,
    const float* __restrict__ Ws2, const float* __restrict__ bs2,
    const float* __restrict__ Wc1, const float* __restrict__ bc1,
    const float* __restrict__ Wc2, const float* __restrict__ bc2,
    const float* __restrict__ att, float* __restrict__ sout,
    float* __restrict__ ec) {
  __shared__ float xg[64], hid[64], sv[5], cl[64];
  int b = blockIdx.x, t = threadIdx.x;
  xg[t] = XG[b * 64 + t];
  __syncthreads();
  float a = bs1[t];
  for (int d = 0; d < 64; ++d) a = fmaf(xg[d], Ws1[t * 64 + d], a);
  hid[t] = fmaxf(a, 0.0f);
  __syncthreads();
  if (t < 5) {
    float l = bs2[t];
    for (int k = 0; k < 64; ++k) l = fmaf(hid[k], Ws2[t * 64 + k], l);
    sv[t] = l;
  }
  __syncthreads();
  if (t == 0) {
    float m = sv[0];
    for (int n = 1; n < 5; ++n) m = fmaxf(m, sv[n]);
    float e[5], ssum = 0.f;
    for (int n = 0; n < 5; ++n) { e[n] = expf(sv[n] - m); ssum += e[n]; }
    for (int n = 0; n < 5; ++n) {
      float v = e[n] / ssum;
      sv[n] = v;
      sout[b * 5 + n] = v;   // second output
    }
  }
  __syncthreads();
  float cacc = bc1[t];
  for (int n = 0; n < 5; ++n) cacc = fmaf(sv[n], Wc1[t * 5 + n], cacc);
  cl[t] = fmaxf(cacc, 0.0f);
  __syncthreads();
  float c2 = bc2[t];
  for (int k = 0; k < 64; ++k) c2 = fmaf(cl[k], Wc2[t * 64 + k], c2);
  float v = c2 * att[256 + t];
#pragma unroll
  for (int o = 32; o; o >>= 1) v += __shfl_xor(v, o);
  if (t == 0) ec[b] = v;
}

// ---------------- fused softmax(e_tilde) @ Z ----------------
// block = 256 (4 waves), 64 i-rows per block, j tiled by 64
__global__ __launch_bounds__(256) void k_main(const float* __restrict__ Z,
    const float* __restrict__ logA, const float* __restrict__ ei,
    const float* __restrict__ ej, const float* __restrict__ ec,
    const float* __restrict__ lam, float* __restrict__ hout) {
  __shared__ float ejs[1024];
  __shared__ float mrow[64], sinv[64];
  __shared__ float pt[64 * 64];    // XOR-swizzled: [r][jj ^ (r&31)]
  __shared__ float4 zt[64 * 32];   // [jj][f/4]
  int tid = threadIdx.x;
  int b = blockIdx.y, i0 = blockIdx.x * 64;
#pragma unroll
  for (int k = 0; k < 4; ++k) ejs[k * 256 + tid] = ej[b * 1024 + k * 256 + tid];
  float lamv = lam[0];
  float ecb = ec[b];
  __syncthreads();

  int wave = tid >> 6, lane = tid & 63;
  // pass 1: per-row max and sum (each wave owns 16 rows)
  for (int rr = 0; rr < 16; ++rr) {
    int r = wave * 16 + rr;
    float eir = ei[b * 1024 + i0 + r];
    const float* lrow = logA + (size_t)(i0 + r) * 1024;
    float tv[16];
    float m = -1e30f;
#pragma unroll
    for (int k = 0; k < 16; ++k) {
      int j = lane + k * 64;
      float t = eir + ejs[j] + ecb;
      t = t > 0.0f ? t : 0.2f * t;          // leaky_relu(0.2)
      t = fmaf(lamv, lrow[j], t);           // + lam*log(A+eps)
      tv[k] = t;
      m = fmaxf(m, t);
    }
#pragma unroll
    for (int o = 32; o; o >>= 1) m = fmaxf(m, __shfl_xor(m, o));
    float s = 0.0f;
#pragma unroll
    for (int k = 0; k < 16; ++k) s += expf(tv[k] - m);
#pragma unroll
    for (int o = 32; o; o >>= 1) s += __shfl_xor(s, o);
    if (lane == 0) { mrow[r] = m; sinv[r] = 1.0f / s; }
  }

  // pass 2: tile over j, accumulate h
  int rp = tid >> 2, jq = (tid & 3) * 16;
  float eir2 = ei[b * 1024 + i0 + rp];
  const float* lrow2 = logA + (size_t)(i0 + rp) * 1024;
  float4 hacc[8];
#pragma unroll
  for (int q = 0; q < 8; ++q) hacc[q] = make_float4(0.f, 0.f, 0.f, 0.f);
  const float4* Zb4 = (const float4*)(Z + (size_t)b * 1024 * 128);

  for (int jt = 0; jt < 16; ++jt) {
    int j0 = jt * 64;
    __syncthreads();   // previous tile's readers done (also fences pass-1 LDS)
    // stage Z tile [64 rows][128 f] = 2048 float4
#pragma unroll
    for (int k = 0; k < 8; ++k)
      zt[k * 256 + tid] = Zb4[j0 * 32 + k * 256 + tid];
    // compute p tile (each thread: one row, 16 jj)
    {
      float mr = mrow[rp], si = sinv[rp];
#pragma unroll
      for (int u = 0; u < 16; ++u) {
        int jj = jq + u;
        int j = j0 + jj;
        float t = eir2 + ejs[j] + ecb;
        t = t > 0.0f ? t : 0.2f * t;
        t = fmaf(lamv, lrow2[j], t);
        pt[rp * 64 + (jj ^ (rp & 31))] = expf(t - mr) * si;
      }
    }
    __syncthreads();
    // h accumulation: thread = (row=lane, f-slice=wave*32)
#pragma unroll 4
    for (int jj = 0; jj < 64; ++jj) {
      float p = pt[lane * 64 + (jj ^ (lane & 31))];
      const float4* zr = zt + jj * 32 + wave * 8;
#pragma unroll
      for (int q = 0; q < 8; ++q) {
        float4 z = zr[q];
        hacc[q].x = fmaf(p, z.x, hacc[q].x);
        hacc[q].y = fmaf(p, z.y, hacc[q].y);
        hacc[q].z = fmaf(p, z.z, hacc[q].z);
        hacc[q].w = fmaf(p, z.w, hacc[q].w);
      }
    }
  }
  float4* hp = (float4*)(hout + ((size_t)b * 1024 + i0 + lane) * 128 + wave * 32);
#pragma unroll
  for (int q = 0; q < 8; ++q) hp[q] = hacc[q];
}

extern "C" void kernel_launch(void* const* d_in, const int* in_sizes, int n_in,
                              void* d_out, int out_size, void* d_ws, size_t ws_size,
                              hipStream_t stream) {
  const float* x     = (const float*)d_in[0];
  const float* Ainit = (const float*)d_in[1];
  const float* Wproj = (const float*)d_in[2];
  const float* bproj = (const float*)d_in[3];
  const float* Ws1   = (const float*)d_in[4];
  const float* bs1   = (const float*)d_in[5];
  const float* Ws2   = (const float*)d_in[6];
  const float* bs2   = (const float*)d_in[7];
  const float* Wc1   = (const float*)d_in[8];
  const float* bc1   = (const float*)d_in[9];
  const float* Wc2   = (const float*)d_in[10];
  const float* bc2   = (const float*)d_in[11];
  const float* att   = (const float*)d_in[12];
  const float* lam   = (const float*)d_in[13];

  float* ws    = (float*)d_ws;
  float* logA  = ws + LOGA_OFF;
  float* xred  = ws + XRED_OFF;
  float* xglob = ws + XGLOB_OFF;
  float* Zb    = ws + Z_OFF;
  float* ei    = ws + EI_OFF;
  float* ej    = ws + EJ_OFF;
  float* ec    = ws + EC_OFF;

  float* hout = (float*)d_out;                  // (32,1024,128)
  float* sout = hout + (size_t)32 * 1024 * 128; // (32,5)

  hipLaunchKernelGGL(k_logA,  dim3(1024),    dim3(256), 0, stream, Ainit, logA);
  hipLaunchKernelGGL(k_xred,  dim3(32768),   dim3(256), 0, stream,
                     (const float4*)x, (float4*)xred);
  hipLaunchKernelGGL(k_xglob, dim3(32),      dim3(256), 0, stream, xred, xglob);
  hipLaunchKernelGGL(k_Z,     dim3(1024),    dim3(256), 0, stream,
                     (const float4*)xred, Wproj, bproj, Zb);
  hipLaunchKernelGGL(k_e,     dim3(8192),    dim3(256), 0, stream, Zb, att, ei, ej);
  hipLaunchKernelGGL(k_small, dim3(32),      dim3(64),  0, stream, xglob,
                     Ws1, bs1, Ws2, bs2, Wc1, bc1, Wc2, bc2, att, sout, ec);
  hipLaunchKernelGGL(k_main,  dim3(16, 32),  dim3(256), 0, stream,
                     Zb, logA, ei, ej, ec, lam, hout);
}

// Round 4
// 416.118 us; speedup vs baseline: 1.2456x; 1.2456x over previous
//
#include <hip/hip_runtime.h>
#include <cstddef>
#include <math.h>

// Problem dims
// B=32, C=1024, T=64, D=64, F_OUT=128, S_DIM=64, N_STG=5, H_MLP=64

// workspace layout (float offsets)
#define LOGA_OFF  0u          // 1024*1024 = 1048576
#define XRED_OFF  1048576u    // 32*1024*64 = 2097152
#define XGLOB_OFF 3145728u    // 32*64 = 2048
#define Z_OFF     3147776u    // 32*1024*128 = 4194304
#define EI_OFF    7342080u    // 32768
#define EJ_OFF    7374848u    // 32768
#define EC_OFF    7407616u    // 32

// ---------------- logA = log(A + 1e-8) ----------------
__global__ __launch_bounds__(256) void k_logA(const float* __restrict__ A,
                                              float* __restrict__ out) {
  int base = blockIdx.x * 1024 + threadIdx.x;
#pragma unroll
  for (int k = 0; k < 4; ++k)
    out[base + k * 256] = logf(A[base + k * 256] + 1e-8f);
}

// ---------------- x_red = mean over T ----------------
// one block per (b,c); 64x64 tile = 1024 float4
__global__ __launch_bounds__(256) void k_xred(const float4* __restrict__ X4,
                                              float4* __restrict__ XR4) {
  __shared__ float4 part[256];
  int bc = blockIdx.x;
  int tid = threadIdx.x;
  int dq = tid & 15, tw = tid >> 4;
  const float4* base = X4 + (size_t)bc * 1024;
  float4 acc = make_float4(0.f, 0.f, 0.f, 0.f);
#pragma unroll
  for (int k = 0; k < 4; ++k) {
    float4 v = base[(tw + k * 16) * 16 + dq];
    acc.x += v.x; acc.y += v.y; acc.z += v.z; acc.w += v.w;
  }
  part[tid] = acc;
  __syncthreads();
  if (tid < 16) {
    float4 s = part[tid];
#pragma unroll
    for (int w = 1; w < 16; ++w) {
      float4 v = part[w * 16 + tid];
      s.x += v.x; s.y += v.y; s.z += v.z; s.w += v.w;
    }
    const float inv = 1.0f / 64.0f;
    s.x *= inv; s.y *= inv; s.z *= inv; s.w *= inv;
    XR4[(size_t)bc * 16 + tid] = s;
  }
}

// ---------------- x_glob = mean over C of x_red ----------------
__global__ __launch_bounds__(256) void k_xglob(const float* __restrict__ XR,
                                               float* __restrict__ XG) {
  __shared__ float part[256];
  int b = blockIdx.x, tid = threadIdx.x;
  int d = tid & 63, cq = tid >> 6;
  float acc = 0.f;
  for (int c = cq; c < 1024; c += 4)
    acc += XR[((size_t)b * 1024 + c) * 64 + d];
  part[tid] = acc;
  __syncthreads();
  if (tid < 64) {
    float s = part[tid] + part[64 + tid] + part[128 + tid] + part[192 + tid];
    XG[b * 64 + tid] = s * (1.0f / 1024.0f);
  }
}

// ---------------- Z = x_red @ W_proj^T + b_proj ----------------
__global__ __launch_bounds__(256) void k_Z(const float4* __restrict__ XR4,
                                           const float* __restrict__ W,
                                           const float* __restrict__ bproj,
                                           float* __restrict__ Z) {
  __shared__ float Wl[64 * 129];
  __shared__ float4 xr4[32 * 16];
  int tid = threadIdx.x;
  int rb = blockIdx.x * 32;
#pragma unroll
  for (int k = 0; k < 32; ++k) {
    int g = k * 256 + tid;         // g = f*64 + d
    Wl[(g & 63) * 129 + (g >> 6)] = W[g];
  }
#pragma unroll
  for (int k = 0; k < 2; ++k)
    xr4[k * 256 + tid] = XR4[(size_t)rb * 16 + k * 256 + tid];
  __syncthreads();

  int f = tid & 127, rg = tid >> 7;
  float wreg[64];
#pragma unroll
  for (int d = 0; d < 64; ++d) wreg[d] = Wl[d * 129 + f];
  float bias = bproj[f];
  float acc[16];
#pragma unroll
  for (int r = 0; r < 16; ++r) acc[r] = bias;
#pragma unroll
  for (int r = 0; r < 16; ++r) {
    int row = rg * 16 + r;
#pragma unroll
    for (int dq = 0; dq < 16; ++dq) {
      float4 xv = xr4[row * 16 + dq];
      acc[r] = fmaf(wreg[dq * 4 + 0], xv.x, acc[r]);
      acc[r] = fmaf(wreg[dq * 4 + 1], xv.y, acc[r]);
      acc[r] = fmaf(wreg[dq * 4 + 2], xv.z, acc[r]);
      acc[r] = fmaf(wreg[dq * 4 + 3], xv.w, acc[r]);
    }
  }
#pragma unroll
  for (int r = 0; r < 16; ++r) {
    int row = rg * 16 + r;
    Z[((size_t)rb + row) * 128 + f] = acc[r];
  }
}

// ---------------- ei = Z@a_i, ej = Z@a_j ----------------
__global__ __launch_bounds__(256) void k_e(const float* __restrict__ Z,
                                           const float* __restrict__ att,
                                           float* __restrict__ ei,
                                           float* __restrict__ ej) {
  int tid = threadIdx.x;
  int row = blockIdx.x * 4 + (tid >> 6);
  int lane = tid & 63;
  float z0 = Z[(size_t)row * 128 + lane];
  float z1 = Z[(size_t)row * 128 + 64 + lane];
  float si = z0 * att[lane] + z1 * att[64 + lane];
  float sj = z0 * att[128 + lane] + z1 * att[192 + lane];
#pragma unroll
  for (int o = 32; o; o >>= 1) {
    si += __shfl_xor(si, o);
    sj += __shfl_xor(sj, o);
  }
  if (lane == 0) { ei[row] = si; ej[row] = sj; }
}

// ---------------- s, c, e_c chain (tiny) ----------------
__global__ __launch_bounds__(64) void k_small(const float* __restrict__ XG,
    const float* __restrict__ Ws1, const float* __restrict__ bs1,
    const float* __restrict__ Ws2, const float* __restrict__ bs2,
    const float* __restrict__ Wc1, const float* __restrict__ bc1,
    const float* __restrict__ Wc2, const float* __restrict__ bc2,
    const float* __restrict__ att, float* __restrict__ sout,
    float* __restrict__ ec) {
  __shared__ float xg[64], hid[64], sv[5], cl[64];
  int b = blockIdx.x, t = threadIdx.x;
  xg[t] = XG[b * 64 + t];
  __syncthreads();
  float a = bs1[t];
  for (int d = 0; d < 64; ++d) a = fmaf(xg[d], Ws1[t * 64 + d], a);
  hid[t] = fmaxf(a, 0.0f);
  __syncthreads();
  if (t < 5) {
    float l = bs2[t];
    for (int k = 0; k < 64; ++k) l = fmaf(hid[k], Ws2[t * 64 + k], l);
    sv[t] = l;
  }
  __syncthreads();
  if (t == 0) {
    float m = sv[0];
    for (int n = 1; n < 5; ++n) m = fmaxf(m, sv[n]);
    float e[5], ssum = 0.f;
    for (int n = 0; n < 5; ++n) { e[n] = expf(sv[n] - m); ssum += e[n]; }
    for (int n = 0; n < 5; ++n) {
      float v = e[n] / ssum;
      sv[n] = v;
      sout[b * 5 + n] = v;
    }
  }
  __syncthreads();
  float cacc = bc1[t];
  for (int n = 0; n < 5; ++n) cacc = fmaf(sv[n], Wc1[t * 5 + n], cacc);
  cl[t] = fmaxf(cacc, 0.0f);
  __syncthreads();
  float c2 = bc2[t];
  for (int k = 0; k < 64; ++k) c2 = fmaf(cl[k], Wc2[t * 64 + k], c2);
  float v = c2 * att[256 + t];
#pragma unroll
  for (int o = 32; o; o >>= 1) v += __shfl_xor(v, o);
  if (t == 0) ec[b] = v;
}

// ---------------- fused softmax(e_tilde) @ Z ----------------
// block = 128 threads (2 waves), 64 i-rows, j tiled by 64.
// Register tile: 8 rows x 8 f per thread (rowgrp=tid>>4 in 0..7, fgrp=tid&15).
// pt transposed [jj][row], stride 68 words (bank rotates by 4 per jj).
// zt half-split [jj][half][fquad] so z b128 reads are stride-4 contiguous.
__global__ __launch_bounds__(128) void k_main(const float* __restrict__ Z,
    const float* __restrict__ logA, const float* __restrict__ ei,
    const float* __restrict__ ej, const float* __restrict__ ec,
    const float* __restrict__ lam, float* __restrict__ hout) {
  __shared__ float4 ejs4[256];                  // ej[b][0..1023]
  __shared__ float pt[64 * 68];                 // [jj][row], stride 68
  __shared__ float4 zt4[2048];                  // [jj][half][fquad]
  __shared__ float mrow[64], sinv[64];

  int tid = threadIdx.x;
  int b = blockIdx.y, i0 = blockIdx.x * 64;
  const float* ejs = (const float*)ejs4;

  // stage ej row for this batch
  const float4* ej4 = (const float4*)(ej + b * 1024);
#pragma unroll
  for (int k = 0; k < 2; ++k) ejs4[k * 128 + tid] = ej4[k * 128 + tid];
  float lamv = lam[0];
  float ecb = ec[b];
  __syncthreads();

  int wave = tid >> 6, lane = tid & 63;
  // ---- pass 1: per-row max and inv-sum (each wave owns 32 rows) ----
  for (int rr = 0; rr < 32; ++rr) {
    int r = wave * 32 + rr;
    float eir = ei[b * 1024 + i0 + r];
    const float* lrow = logA + (size_t)(i0 + r) * 1024;
    float tv[16];
    float m = -1e30f;
#pragma unroll
    for (int k = 0; k < 16; ++k) {
      int j = lane + k * 64;
      float t = eir + ejs[j] + ecb;
      t = t > 0.0f ? t : 0.2f * t;          // leaky_relu(0.2)
      t = fmaf(lamv, lrow[j], t);           // + lam*log(A+eps)
      tv[k] = t;
      m = fmaxf(m, t);
    }
#pragma unroll
    for (int o = 32; o; o >>= 1) m = fmaxf(m, __shfl_xor(m, o));
    float s = 0.0f;
#pragma unroll
    for (int k = 0; k < 16; ++k) s += expf(tv[k] - m);
#pragma unroll
    for (int o = 32; o; o >>= 1) s += __shfl_xor(s, o);
    if (lane == 0) { mrow[r] = m; sinv[r] = 1.0f / s; }
  }
  __syncthreads();

  // ---- pass 2: tile over j, accumulate h with 8x8 register tile ----
  int prow = tid >> 1, pjq = (tid & 1) * 32;    // p-producer mapping
  float eir2 = ei[b * 1024 + i0 + prow];
  float mr = mrow[prow], si = sinv[prow];
  const float4* lrow4 = (const float4*)(logA + (size_t)(i0 + prow) * 1024);

  int rowgrp = tid >> 4, fgrp = tid & 15;       // consumer mapping
  float4 hacc[8][2];
#pragma unroll
  for (int r = 0; r < 8; ++r) {
    hacc[r][0] = make_float4(0.f, 0.f, 0.f, 0.f);
    hacc[r][1] = make_float4(0.f, 0.f, 0.f, 0.f);
  }
  const float4* Zb4 = (const float4*)(Z + (size_t)b * 1024 * 128);

  for (int jt = 0; jt < 16; ++jt) {
    int j0 = jt * 64;
    __syncthreads();   // previous tile's readers done
    // stage Z tile: 64 rows x 32 quads, half-split layout
#pragma unroll
    for (int k = 0; k < 16; ++k) {
      int idx = k * 128 + tid;        // jj*32 + g
      int jj = idx >> 5, g = idx & 31;
      zt4[jj * 32 + (g & 1) * 16 + (g >> 1)] = Zb4[(j0 + jj) * 32 + g];
    }
    // compute p tile: thread owns row=prow, 32 consecutive jj
    {
      int jb = (j0 + pjq) >> 2;       // float4 index into row
#pragma unroll
      for (int u = 0; u < 8; ++u) {
        float4 la = lrow4[jb + u];
        float4 ev = ejs4[jb + u];
        float t0 = eir2 + ev.x + ecb; t0 = t0 > 0.f ? t0 : 0.2f * t0;
        float t1 = eir2 + ev.y + ecb; t1 = t1 > 0.f ? t1 : 0.2f * t1;
        float t2 = eir2 + ev.z + ecb; t2 = t2 > 0.f ? t2 : 0.2f * t2;
        float t3 = eir2 + ev.w + ecb; t3 = t3 > 0.f ? t3 : 0.2f * t3;
        t0 = fmaf(lamv, la.x, t0); t1 = fmaf(lamv, la.y, t1);
        t2 = fmaf(lamv, la.z, t2); t3 = fmaf(lamv, la.w, t3);
        int jj = pjq + u * 4;
        pt[(jj + 0) * 68 + prow] = expf(t0 - mr) * si;
        pt[(jj + 1) * 68 + prow] = expf(t1 - mr) * si;
        pt[(jj + 2) * 68 + prow] = expf(t2 - mr) * si;
        pt[(jj + 3) * 68 + prow] = expf(t3 - mr) * si;
      }
    }
    __syncthreads();
    // acc: per jj: 2 b128 p (8 rows) + 2 b128 z (8 f) -> 64 FMA
#pragma unroll 4
    for (int jj = 0; jj < 64; ++jj) {
      float4 pA = ((const float4*)pt)[jj * 17 + rowgrp * 2];
      float4 pB = ((const float4*)pt)[jj * 17 + rowgrp * 2 + 1];
      float4 zA = zt4[jj * 32 + fgrp];
      float4 zB = zt4[jj * 32 + 16 + fgrp];
      float pr;
#define ACC_ROW(r, PV) \
      pr = (PV); \
      hacc[r][0].x = fmaf(pr, zA.x, hacc[r][0].x); \
      hacc[r][0].y = fmaf(pr, zA.y, hacc[r][0].y); \
      hacc[r][0].z = fmaf(pr, zA.z, hacc[r][0].z); \
      hacc[r][0].w = fmaf(pr, zA.w, hacc[r][0].w); \
      hacc[r][1].x = fmaf(pr, zB.x, hacc[r][1].x); \
      hacc[r][1].y = fmaf(pr, zB.y, hacc[r][1].y); \
      hacc[r][1].z = fmaf(pr, zB.z, hacc[r][1].z); \
      hacc[r][1].w = fmaf(pr, zB.w, hacc[r][1].w);
      ACC_ROW(0, pA.x) ACC_ROW(1, pA.y) ACC_ROW(2, pA.z) ACC_ROW(3, pA.w)
      ACC_ROW(4, pB.x) ACC_ROW(5, pB.y) ACC_ROW(6, pB.z) ACC_ROW(7, pB.w)
#undef ACC_ROW
    }
  }

  // write out: 8 rows x 8 f per thread
#pragma unroll
  for (int r = 0; r < 8; ++r) {
    int grow = i0 + rowgrp * 8 + r;
    float4* o = (float4*)(hout + ((size_t)b * 1024 + grow) * 128 + fgrp * 8);
    o[0] = hacc[r][0];
    o[1] = hacc[r][1];
  }
}

extern "C" void kernel_launch(void* const* d_in, const int* in_sizes, int n_in,
                              void* d_out, int out_size, void* d_ws, size_t ws_size,
                              hipStream_t stream) {
  const float* x     = (const float*)d_in[0];
  const float* Ainit = (const float*)d_in[1];
  const float* Wproj = (const float*)d_in[2];
  const float* bproj = (const float*)d_in[3];
  const float* Ws1   = (const float*)d_in[4];
  const float* bs1   = (const float*)d_in[5];
  const float* Ws2   = (const float*)d_in[6];
  const float* bs2   = (const float*)d_in[7];
  const float* Wc1   = (const float*)d_in[8];
  const float* bc1   = (const float*)d_in[9];
  const float* Wc2   = (const float*)d_in[10];
  const float* bc2   = (const float*)d_in[11];
  const float* att   = (const float*)d_in[12];
  const float* lam   = (const float*)d_in[13];

  float* ws    = (float*)d_ws;
  float* logA  = ws + LOGA_OFF;
  float* xred  = ws + XRED_OFF;
  float* xglob = ws + XGLOB_OFF;
  float* Zb    = ws + Z_OFF;
  float* ei    = ws + EI_OFF;
  float* ej    = ws + EJ_OFF;
  float* ec    = ws + EC_OFF;

  float* hout = (float*)d_out;                  // (32,1024,128)
  float* sout = hout + (size_t)32 * 1024 * 128; // (32,5)

  hipLaunchKernelGGL(k_logA,  dim3(1024),    dim3(256), 0, stream, Ainit, logA);
  hipLaunchKernelGGL(k_xred,  dim3(32768),   dim3(256), 0, stream,
                     (const float4*)x, (float4*)xred);
  hipLaunchKernelGGL(k_xglob, dim3(32),      dim3(256), 0, stream, xred, xglob);
  hipLaunchKernelGGL(k_Z,     dim3(1024),    dim3(256), 0, stream,
                     (const float4*)xred, Wproj, bproj, Zb);
  hipLaunchKernelGGL(k_e,     dim3(8192),    dim3(256), 0, stream, Zb, att, ei, ej);
  hipLaunchKernelGGL(k_small, dim3(32),      dim3(64),  0, stream, xglob,
                     Ws1, bs1, Ws2, bs2, Wc1, bc1, Wc2, bc2, att, sout, ec);
  hipLaunchKernelGGL(k_main,  dim3(16, 32),  dim3(128), 0, stream,
                     Zb, logA, ei, ej, ec, lam, hout);
}

// Round 5
// 342.284 us; speedup vs baseline: 1.5143x; 1.2157x over previous
//
#include <hip/hip_runtime.h>
#include <cstddef>
#include <math.h>

// Problem dims
// B=32, C=1024, T=64, D=64, F_OUT=128, S_DIM=64, N_STG=5, H_MLP=64

typedef __attribute__((ext_vector_type(8))) short bf16x8;
typedef __attribute__((ext_vector_type(4))) float f32x4;

__device__ inline unsigned f2bf(float f) {
  unsigned u = __float_as_uint(f);
  return (u + 0x7FFFu + ((u >> 16) & 1u)) >> 16;   // RTN-even
}

// workspace layout (float offsets)
#define LOGA_OFF  0u          // 1024*1024 = 1048576
#define XRED_OFF  1048576u    // 32*1024*64 = 2097152
#define XGLOB_OFF 3145728u    // 32*64 = 2048
#define Z_OFF     3147776u    // 32*1024*128 = 4194304 (fp32, for k_e)
#define EI_OFF    7342080u    // 32768
#define EJ_OFF    7374848u    // 32768
#define EC_OFF    7407616u    // 32
#define ZK_OFF    7407648u    // bf16 k-major Z: 32*1024*128 bf16 = 2097152 floats

// ---------------- logA = log(A + 1e-8) ----------------
__global__ __launch_bounds__(256) void k_logA(const float* __restrict__ A,
                                              float* __restrict__ out) {
  int base = blockIdx.x * 1024 + threadIdx.x;
#pragma unroll
  for (int k = 0; k < 4; ++k)
    out[base + k * 256] = logf(A[base + k * 256] + 1e-8f);
}

// ---------------- x_red = mean over T ----------------
__global__ __launch_bounds__(256) void k_xred(const float4* __restrict__ X4,
                                              float4* __restrict__ XR4) {
  __shared__ float4 part[256];
  int bc = blockIdx.x;
  int tid = threadIdx.x;
  int dq = tid & 15, tw = tid >> 4;
  const float4* base = X4 + (size_t)bc * 1024;
  float4 acc = make_float4(0.f, 0.f, 0.f, 0.f);
#pragma unroll
  for (int k = 0; k < 4; ++k) {
    float4 v = base[(tw + k * 16) * 16 + dq];
    acc.x += v.x; acc.y += v.y; acc.z += v.z; acc.w += v.w;
  }
  part[tid] = acc;
  __syncthreads();
  if (tid < 16) {
    float4 s = part[tid];
#pragma unroll
    for (int w = 1; w < 16; ++w) {
      float4 v = part[w * 16 + tid];
      s.x += v.x; s.y += v.y; s.z += v.z; s.w += v.w;
    }
    const float inv = 1.0f / 64.0f;
    s.x *= inv; s.y *= inv; s.z *= inv; s.w *= inv;
    XR4[(size_t)bc * 16 + tid] = s;
  }
}

// ---------------- x_glob = mean over C of x_red ----------------
__global__ __launch_bounds__(256) void k_xglob(const float* __restrict__ XR,
                                               float* __restrict__ XG) {
  __shared__ float part[256];
  int b = blockIdx.x, tid = threadIdx.x;
  int d = tid & 63, cq = tid >> 6;
  float acc = 0.f;
  for (int c = cq; c < 1024; c += 4)
    acc += XR[((size_t)b * 1024 + c) * 64 + d];
  part[tid] = acc;
  __syncthreads();
  if (tid < 64) {
    float s = part[tid] + part[64 + tid] + part[128 + tid] + part[192 + tid];
    XG[b * 64 + tid] = s * (1.0f / 1024.0f);
  }
}

// ---------------- Z = x_red @ W_proj^T + b_proj ----------------
// Writes fp32 Z (for k_e) AND bf16 Zk in k-major chunked layout
// Zk[b][jgrp=c/8][f][ju=c&7], 16B chunks: chunk = (b*128+jgrp)*128 + f
__global__ __launch_bounds__(256) void k_Z(const float4* __restrict__ XR4,
                                           const float* __restrict__ W,
                                           const float* __restrict__ bproj,
                                           float* __restrict__ Z,
                                           uint4* __restrict__ Zk) {
  __shared__ float Wl[64 * 129];
  __shared__ float4 xr4[32 * 16];
  int tid = threadIdx.x;
  int rb = blockIdx.x * 32;
#pragma unroll
  for (int k = 0; k < 32; ++k) {
    int g = k * 256 + tid;         // g = f*64 + d
    Wl[(g & 63) * 129 + (g >> 6)] = W[g];
  }
#pragma unroll
  for (int k = 0; k < 2; ++k)
    xr4[k * 256 + tid] = XR4[(size_t)rb * 16 + k * 256 + tid];
  __syncthreads();

  int f = tid & 127, rg = tid >> 7;
  float wreg[64];
#pragma unroll
  for (int d = 0; d < 64; ++d) wreg[d] = Wl[d * 129 + f];
  float bias = bproj[f];
  float acc[16];
#pragma unroll
  for (int r = 0; r < 16; ++r) acc[r] = bias;
#pragma unroll
  for (int r = 0; r < 16; ++r) {
    int row = rg * 16 + r;
#pragma unroll
    for (int dq = 0; dq < 16; ++dq) {
      float4 xv = xr4[row * 16 + dq];
      acc[r] = fmaf(wreg[dq * 4 + 0], xv.x, acc[r]);
      acc[r] = fmaf(wreg[dq * 4 + 1], xv.y, acc[r]);
      acc[r] = fmaf(wreg[dq * 4 + 2], xv.z, acc[r]);
      acc[r] = fmaf(wreg[dq * 4 + 3], xv.w, acc[r]);
    }
  }
#pragma unroll
  for (int r = 0; r < 16; ++r) {
    int row = rg * 16 + r;
    Z[((size_t)rb + row) * 128 + f] = acc[r];
  }
  // bf16 k-major chunks: rows rb+rg*16+k2*8+ju, element ju within chunk
  int b = rb >> 10;
  int cbase = (rb & 1023) + rg * 16;
#pragma unroll
  for (int k2 = 0; k2 < 2; ++k2) {
    unsigned w0 = f2bf(acc[k2 * 8 + 0]) | (f2bf(acc[k2 * 8 + 1]) << 16);
    unsigned w1 = f2bf(acc[k2 * 8 + 2]) | (f2bf(acc[k2 * 8 + 3]) << 16);
    unsigned w2 = f2bf(acc[k2 * 8 + 4]) | (f2bf(acc[k2 * 8 + 5]) << 16);
    unsigned w3 = f2bf(acc[k2 * 8 + 6]) | (f2bf(acc[k2 * 8 + 7]) << 16);
    size_t chunk = ((size_t)b * 128 + ((cbase >> 3) + k2)) * 128 + f;
    Zk[chunk] = make_uint4(w0, w1, w2, w3);
  }
}

// ---------------- ei = Z@a_i, ej = Z@a_j ----------------
__global__ __launch_bounds__(256) void k_e(const float* __restrict__ Z,
                                           const float* __restrict__ att,
                                           float* __restrict__ ei,
                                           float* __restrict__ ej) {
  int tid = threadIdx.x;
  int row = blockIdx.x * 4 + (tid >> 6);
  int lane = tid & 63;
  float z0 = Z[(size_t)row * 128 + lane];
  float z1 = Z[(size_t)row * 128 + 64 + lane];
  float si = z0 * att[lane] + z1 * att[64 + lane];
  float sj = z0 * att[128 + lane] + z1 * att[192 + lane];
#pragma unroll
  for (int o = 32; o; o >>= 1) {
    si += __shfl_xor(si, o);
    sj += __shfl_xor(sj, o);
  }
  if (lane == 0) { ei[row] = si; ej[row] = sj; }
}

// ---------------- s, c, e_c chain (tiny) ----------------
__global__ __launch_bounds__(64) void k_small(const float* __restrict__ XG,
    const float* __restrict__ Ws1, const float* __restrict__ bs1,
    const float* __restrict__ Ws2, const float* __restrict__ bs2,
    const float* __restrict__ Wc1, const float* __restrict__ bc1,
    const float* __restrict__ Wc2, const float* __restrict__ bc2,
    const float* __restrict__ att, float* __restrict__ sout,
    float* __restrict__ ec) {
  __shared__ float xg[64], hid[64], sv[5], cl[64];
  int b = blockIdx.x, t = threadIdx.x;
  xg[t] = XG[b * 64 + t];
  __syncthreads();
  float a = bs1[t];
  for (int d = 0; d < 64; ++d) a = fmaf(xg[d], Ws1[t * 64 + d], a);
  hid[t] = fmaxf(a, 0.0f);
  __syncthreads();
  if (t < 5) {
    float l = bs2[t];
    for (int k = 0; k < 64; ++k) l = fmaf(hid[k], Ws2[t * 64 + k], l);
    sv[t] = l;
  }
  __syncthreads();
  if (t == 0) {
    float m = sv[0];
    for (int n = 1; n < 5; ++n) m = fmaxf(m, sv[n]);
    float e[5], ssum = 0.f;
    for (int n = 0; n < 5; ++n) { e[n] = expf(sv[n] - m); ssum += e[n]; }
    for (int n = 0; n < 5; ++n) {
      float v = e[n] / ssum;
      sv[n] = v;
      sout[b * 5 + n] = v;
    }
  }
  __syncthreads();
  float cacc = bc1[t];
  for (int n = 0; n < 5; ++n) cacc = fmaf(sv[n], Wc1[t * 5 + n], cacc);
  cl[t] = fmaxf(cacc, 0.0f);
  __syncthreads();
  float c2 = bc2[t];
  for (int k = 0; k < 64; ++k) c2 = fmaf(cl[k], Wc2[t * 64 + k], c2);
  float v = c2 * att[256 + t];
#pragma unroll
  for (int o = 32; o; o >>= 1) v += __shfl_xor(v, o);
  if (t == 0) ec[b] = v;
}

// ---------------- fused softmax(e_tilde) @ Z via MFMA ----------------
// 256 threads = 4 waves; 64 i-rows per block (16 per wave), full f=128.
// Softmax fp32 (identical to previous passing kernel); PV in bf16 MFMA
// (16x16x32), fp32 accumulate.
// A-frag: lane holds P[row = ln][k = lg*8 + u] (fp32->bf16, reg-built).
// B-frag: ds_read_b128 from LDS region (ksub,fblk): lane-linear 16B chunks
//         holding Z[j0+ksub*32+lg*8+u][fblk*16+ln], staged from k-major Zk.
// C/D (verified): col = lane&15, row = (lane>>4)*4 + reg.
__global__ __launch_bounds__(256) void k_main(const uint4* __restrict__ Zk,
    const float* __restrict__ logA, const float* __restrict__ ei,
    const float* __restrict__ ej, const float* __restrict__ ec,
    const float* __restrict__ lam, float* __restrict__ hout) {
  __shared__ float4 ejs4[256];
  __shared__ float mrow[64], sinv[64];
  __shared__ __align__(16) short zt[8192];   // 16 regions x 64 lanes x 8 bf16

  int tid = threadIdx.x;
  int b = blockIdx.y, i0 = blockIdx.x * 64;
  const float* ejs = (const float*)ejs4;

  const float4* ej4 = (const float4*)(ej + b * 1024);
  ejs4[tid] = ej4[tid];
  float lamv = lam[0];
  float ecb = ec[b];
  __syncthreads();

  int wave = tid >> 6, lane = tid & 63;

  // ---- pass 1: per-row max & inv-sum (wave w owns rows w*16..+15) ----
  for (int rr = 0; rr < 16; ++rr) {
    int r = wave * 16 + rr;
    float eir = ei[b * 1024 + i0 + r];
    const float* lrow = logA + (size_t)(i0 + r) * 1024;
    float tv[16];
    float m = -1e30f;
#pragma unroll
    for (int k = 0; k < 16; ++k) {
      int j = lane + k * 64;
      float t = eir + ejs[j] + ecb;
      t = t > 0.0f ? t : 0.2f * t;          // leaky_relu(0.2)
      t = fmaf(lamv, lrow[j], t);           // + lam*log(A+eps)
      tv[k] = t; m = fmaxf(m, t);
    }
#pragma unroll
    for (int o = 32; o; o >>= 1) m = fmaxf(m, __shfl_xor(m, o));
    float s = 0.0f;
#pragma unroll
    for (int k = 0; k < 16; ++k) s += expf(tv[k] - m);
#pragma unroll
    for (int o = 32; o; o >>= 1) s += __shfl_xor(s, o);
    if (lane == 0) { mrow[r] = m; sinv[r] = 1.0f / s; }
  }
  __syncthreads();

  // ---- pass 2: MFMA over j-tiles of 64 ----
  int lg = lane >> 4, ln = lane & 15;
  int i_gl = i0 + wave * 16 + ln;            // this lane's A-row
  float eir2 = ei[b * 1024 + i_gl];
  float mr = mrow[wave * 16 + ln];
  float si = sinv[wave * 16 + ln];
  const float4* lrow4 = (const float4*)(logA + (size_t)i_gl * 1024);
  const uint4* ZkB = Zk + (size_t)b * 128 * 128;

  f32x4 acc[8];
#pragma unroll
  for (int q = 0; q < 8; ++q) { f32x4 z = {0.f, 0.f, 0.f, 0.f}; acc[q] = z; }

  for (int jt = 0; jt < 16; ++jt) {
    int j0 = jt * 64;
    // issue staging loads (wave w stages regions w*4 .. w*4+3)
    uint4 sv[4];
#pragma unroll
    for (int q = 0; q < 4; ++q) {
      int rgi = wave * 4 + q;
      int ks = rgi >> 3, fb = rgi & 7;
      int jgrp = (j0 >> 3) + ks * 4 + lg;
      sv[q] = ZkB[(size_t)jgrp * 128 + fb * 16 + ln];
    }
    // build P fragments in registers (fp32, identical formula to pass 1)
    bf16x8 pf[2];
#pragma unroll
    for (int ks = 0; ks < 2; ++ks) {
      int jb = (j0 + ks * 32 + lg * 8) >> 2;
      float4 la0 = lrow4[jb], la1 = lrow4[jb + 1];
      float4 e0 = ejs4[jb], e1 = ejs4[jb + 1];
      float eq[8] = {e0.x, e0.y, e0.z, e0.w, e1.x, e1.y, e1.z, e1.w};
      float lq[8] = {la0.x, la0.y, la0.z, la0.w, la1.x, la1.y, la1.z, la1.w};
      unsigned pw[4];
#pragma unroll
      for (int q = 0; q < 4; ++q) {
        float t0 = eir2 + eq[2 * q] + ecb;     t0 = t0 > 0.f ? t0 : 0.2f * t0;
        float t1 = eir2 + eq[2 * q + 1] + ecb; t1 = t1 > 0.f ? t1 : 0.2f * t1;
        t0 = fmaf(lamv, lq[2 * q], t0);
        t1 = fmaf(lamv, lq[2 * q + 1], t1);
        float p0 = expf(t0 - mr) * si;
        float p1 = expf(t1 - mr) * si;
        pw[q] = f2bf(p0) | (f2bf(p1) << 16);
      }
      union { uint4 u; bf16x8 v; } cvt;
      cvt.u = make_uint4(pw[0], pw[1], pw[2], pw[3]);
      pf[ks] = cvt.v;
    }
    __syncthreads();   // prev tile's B-frag reads complete
#pragma unroll
    for (int q = 0; q < 4; ++q)
      *(uint4*)(&zt[(wave * 4 + q) * 512 + lane * 8]) = sv[q];
    __syncthreads();   // staging visible
#pragma unroll
    for (int ks = 0; ks < 2; ++ks) {
#pragma unroll
      for (int fb = 0; fb < 8; ++fb) {
        bf16x8 bz = *(const bf16x8*)(&zt[(ks * 8 + fb) * 512 + lane * 8]);
        acc[fb] = __builtin_amdgcn_mfma_f32_16x16x32_bf16(pf[ks], bz, acc[fb], 0, 0, 0);
      }
    }
  }

  // epilogue: D[row = lg*4+r][col = ln] per 16x16 fragment fb
  float* hb = hout + ((size_t)b * 1024 + i0 + wave * 16 + lg * 4) * 128 + ln;
#pragma unroll
  for (int fb = 0; fb < 8; ++fb) {
#pragma unroll
    for (int r = 0; r < 4; ++r)
      hb[(size_t)r * 128 + fb * 16] = acc[fb][r];
  }
}

extern "C" void kernel_launch(void* const* d_in, const int* in_sizes, int n_in,
                              void* d_out, int out_size, void* d_ws, size_t ws_size,
                              hipStream_t stream) {
  const float* x     = (const float*)d_in[0];
  const float* Ainit = (const float*)d_in[1];
  const float* Wproj = (const float*)d_in[2];
  const float* bproj = (const float*)d_in[3];
  const float* Ws1   = (const float*)d_in[4];
  const float* bs1   = (const float*)d_in[5];
  const float* Ws2   = (const float*)d_in[6];
  const float* bs2   = (const float*)d_in[7];
  const float* Wc1   = (const float*)d_in[8];
  const float* bc1   = (const float*)d_in[9];
  const float* Wc2   = (const float*)d_in[10];
  const float* bc2   = (const float*)d_in[11];
  const float* att   = (const float*)d_in[12];
  const float* lam   = (const float*)d_in[13];

  float* ws    = (float*)d_ws;
  float* logA  = ws + LOGA_OFF;
  float* xred  = ws + XRED_OFF;
  float* xglob = ws + XGLOB_OFF;
  float* Zb    = ws + Z_OFF;
  float* ei    = ws + EI_OFF;
  float* ej    = ws + EJ_OFF;
  float* ec    = ws + EC_OFF;
  uint4* Zk    = (uint4*)(ws + ZK_OFF);

  float* hout = (float*)d_out;                  // (32,1024,128)
  float* sout = hout + (size_t)32 * 1024 * 128; // (32,5)

  hipLaunchKernelGGL(k_logA,  dim3(1024),    dim3(256), 0, stream, Ainit, logA);
  hipLaunchKernelGGL(k_xred,  dim3(32768),   dim3(256), 0, stream,
                     (const float4*)x, (float4*)xred);
  hipLaunchKernelGGL(k_xglob, dim3(32),      dim3(256), 0, stream, xred, xglob);
  hipLaunchKernelGGL(k_Z,     dim3(1024),    dim3(256), 0, stream,
                     (const float4*)xred, Wproj, bproj, Zb, Zk);
  hipLaunchKernelGGL(k_e,     dim3(8192),    dim3(256), 0, stream, Zb, att, ei, ej);
  hipLaunchKernelGGL(k_small, dim3(32),      dim3(64),  0, stream, xglob,
                     Ws1, bs1, Ws2, bs2, Wc1, bc1, Wc2, bc2, att, sout, ec);
  hipLaunchKernelGGL(k_main,  dim3(16, 32),  dim3(256), 0, stream,
                     Zk, logA, ei, ej, ec, lam, hout);
}

// Round 6
// 338.547 us; speedup vs baseline: 1.5310x; 1.0110x over previous
//
#include <hip/hip_runtime.h>
#include <cstddef>
#include <math.h>

// Problem dims
// B=32, C=1024, T=64, D=64, F_OUT=128, S_DIM=64, N_STG=5, H_MLP=64

typedef __attribute__((ext_vector_type(8))) short bf16x8;
typedef __attribute__((ext_vector_type(4))) float f32x4;

__device__ inline unsigned f2bf(float f) {
  unsigned u = __float_as_uint(f);
  return (u + 0x7FFFu + ((u >> 16) & 1u)) >> 16;   // RTN-even
}

// lgkm-only barrier: does NOT drain vmcnt -> global prefetches stay in flight
#define LGKM_BARRIER() asm volatile("s_waitcnt lgkmcnt(0)\n\ts_barrier" ::: "memory")

// workspace layout (float offsets)
#define LOGA_OFF  0u          // 1024*1024 = 1048576
#define XRED_OFF  1048576u    // 32*1024*64 = 2097152
#define XGLOB_OFF 3145728u    // 32*64 = 2048
#define Z_OFF     3147776u    // 32*1024*128 = 4194304 (fp32, for k_e)
#define EI_OFF    7342080u    // 32768
#define EJ_OFF    7374848u    // 32768
#define EC_OFF    7407616u    // 32
#define ZK_OFF    7407648u    // bf16 k-major Z: 32*1024*128 bf16 = 2097152 floats

// ---------------- logA = log(A + 1e-8) ----------------
__global__ __launch_bounds__(256) void k_logA(const float* __restrict__ A,
                                              float* __restrict__ out) {
  int base = blockIdx.x * 1024 + threadIdx.x;
#pragma unroll
  for (int k = 0; k < 4; ++k)
    out[base + k * 256] = logf(A[base + k * 256] + 1e-8f);
}

// ---------------- x_red = mean over T (pure stream, no LDS) ----------------
// block handles 16 (b,c) rows; thread = (c_local = tid>>4, dq = tid&15);
// 64 float4 loads per thread, 4 accumulators for MLP.
__global__ __launch_bounds__(256) void k_xred(const float4* __restrict__ X4,
                                              float4* __restrict__ XR4) {
  int tid = threadIdx.x;
  int cl = tid >> 4, dq = tid & 15;
  size_t row = (size_t)blockIdx.x * 16 + cl;     // b*1024 + c
  const float4* base = X4 + row * 1024 + dq;     // + t*16 per step
  float4 a0 = make_float4(0.f, 0.f, 0.f, 0.f);
  float4 a1 = a0, a2 = a0, a3 = a0;
#pragma unroll
  for (int t = 0; t < 64; t += 4) {
    float4 v0 = base[(t + 0) * 16];
    float4 v1 = base[(t + 1) * 16];
    float4 v2 = base[(t + 2) * 16];
    float4 v3 = base[(t + 3) * 16];
    a0.x += v0.x; a0.y += v0.y; a0.z += v0.z; a0.w += v0.w;
    a1.x += v1.x; a1.y += v1.y; a1.z += v1.z; a1.w += v1.w;
    a2.x += v2.x; a2.y += v2.y; a2.z += v2.z; a2.w += v2.w;
    a3.x += v3.x; a3.y += v3.y; a3.z += v3.z; a3.w += v3.w;
  }
  const float inv = 1.0f / 64.0f;
  float4 s;
  s.x = ((a0.x + a1.x) + (a2.x + a3.x)) * inv;
  s.y = ((a0.y + a1.y) + (a2.y + a3.y)) * inv;
  s.z = ((a0.z + a1.z) + (a2.z + a3.z)) * inv;
  s.w = ((a0.w + a1.w) + (a2.w + a3.w)) * inv;
  XR4[row * 16 + dq] = s;
}

// ---------------- x_glob = mean over C of x_red ----------------
__global__ __launch_bounds__(256) void k_xglob(const float* __restrict__ XR,
                                               float* __restrict__ XG) {
  __shared__ float part[256];
  int b = blockIdx.x, tid = threadIdx.x;
  int d = tid & 63, cq = tid >> 6;
  float acc = 0.f;
  for (int c = cq; c < 1024; c += 4)
    acc += XR[((size_t)b * 1024 + c) * 64 + d];
  part[tid] = acc;
  __syncthreads();
  if (tid < 64) {
    float s = part[tid] + part[64 + tid] + part[128 + tid] + part[192 + tid];
    XG[b * 64 + tid] = s * (1.0f / 1024.0f);
  }
}

// ---------------- Z = x_red @ W_proj^T + b_proj ----------------
// Writes fp32 Z (for k_e) AND bf16 Zk in k-major chunked layout
// Zk[b][jgrp=c/8][f][ju=c&7], 16B chunks: chunk = (b*128+jgrp)*128 + f
__global__ __launch_bounds__(256) void k_Z(const float4* __restrict__ XR4,
                                           const float* __restrict__ W,
                                           const float* __restrict__ bproj,
                                           float* __restrict__ Z,
                                           uint4* __restrict__ Zk) {
  __shared__ float Wl[64 * 129];
  __shared__ float4 xr4[32 * 16];
  int tid = threadIdx.x;
  int rb = blockIdx.x * 32;
#pragma unroll
  for (int k = 0; k < 32; ++k) {
    int g = k * 256 + tid;         // g = f*64 + d
    Wl[(g & 63) * 129 + (g >> 6)] = W[g];
  }
#pragma unroll
  for (int k = 0; k < 2; ++k)
    xr4[k * 256 + tid] = XR4[(size_t)rb * 16 + k * 256 + tid];
  __syncthreads();

  int f = tid & 127, rg = tid >> 7;
  float wreg[64];
#pragma unroll
  for (int d = 0; d < 64; ++d) wreg[d] = Wl[d * 129 + f];
  float bias = bproj[f];
  float acc[16];
#pragma unroll
  for (int r = 0; r < 16; ++r) acc[r] = bias;
#pragma unroll
  for (int r = 0; r < 16; ++r) {
    int row = rg * 16 + r;
#pragma unroll
    for (int dq = 0; dq < 16; ++dq) {
      float4 xv = xr4[row * 16 + dq];
      acc[r] = fmaf(wreg[dq * 4 + 0], xv.x, acc[r]);
      acc[r] = fmaf(wreg[dq * 4 + 1], xv.y, acc[r]);
      acc[r] = fmaf(wreg[dq * 4 + 2], xv.z, acc[r]);
      acc[r] = fmaf(wreg[dq * 4 + 3], xv.w, acc[r]);
    }
  }
#pragma unroll
  for (int r = 0; r < 16; ++r) {
    int row = rg * 16 + r;
    Z[((size_t)rb + row) * 128 + f] = acc[r];
  }
  int b = rb >> 10;
  int cbase = (rb & 1023) + rg * 16;
#pragma unroll
  for (int k2 = 0; k2 < 2; ++k2) {
    unsigned w0 = f2bf(acc[k2 * 8 + 0]) | (f2bf(acc[k2 * 8 + 1]) << 16);
    unsigned w1 = f2bf(acc[k2 * 8 + 2]) | (f2bf(acc[k2 * 8 + 3]) << 16);
    unsigned w2 = f2bf(acc[k2 * 8 + 4]) | (f2bf(acc[k2 * 8 + 5]) << 16);
    unsigned w3 = f2bf(acc[k2 * 8 + 6]) | (f2bf(acc[k2 * 8 + 7]) << 16);
    size_t chunk = ((size_t)b * 128 + ((cbase >> 3) + k2)) * 128 + f;
    Zk[chunk] = make_uint4(w0, w1, w2, w3);
  }
}

// ---------------- ei = Z@a_i, ej = Z@a_j ----------------
__global__ __launch_bounds__(256) void k_e(const float* __restrict__ Z,
                                           const float* __restrict__ att,
                                           float* __restrict__ ei,
                                           float* __restrict__ ej) {
  int tid = threadIdx.x;
  int row = blockIdx.x * 4 + (tid >> 6);
  int lane = tid & 63;
  float z0 = Z[(size_t)row * 128 + lane];
  float z1 = Z[(size_t)row * 128 + 64 + lane];
  float si = z0 * att[lane] + z1 * att[64 + lane];
  float sj = z0 * att[128 + lane] + z1 * att[192 + lane];
#pragma unroll
  for (int o = 32; o; o >>= 1) {
    si += __shfl_xor(si, o);
    sj += __shfl_xor(sj, o);
  }
  if (lane == 0) { ei[row] = si; ej[row] = sj; }
}

// ---------------- s, c, e_c chain (tiny) ----------------
__global__ __launch_bounds__(64) void k_small(const float* __restrict__ XG,
    const float* __restrict__ Ws1, const float* __restrict__ bs1,
    const float* __restrict__ Ws2, const float* __restrict__ bs2,
    const float* __restrict__ Wc1, const float* __restrict__ bc1,
    const float* __restrict__ Wc2, const float* __restrict__ bc2,
    const float* __restrict__ att, float* __restrict__ sout,
    float* __restrict__ ec) {
  __shared__ float xg[64], hid[64], sv[5], cl[64];
  int b = blockIdx.x, t = threadIdx.x;
  xg[t] = XG[b * 64 + t];
  __syncthreads();
  float a = bs1[t];
  for (int d = 0; d < 64; ++d) a = fmaf(xg[d], Ws1[t * 64 + d], a);
  hid[t] = fmaxf(a, 0.0f);
  __syncthreads();
  if (t < 5) {
    float l = bs2[t];
    for (int k = 0; k < 64; ++k) l = fmaf(hid[k], Ws2[t * 64 + k], l);
    sv[t] = l;
  }
  __syncthreads();
  if (t == 0) {
    float m = sv[0];
    for (int n = 1; n < 5; ++n) m = fmaxf(m, sv[n]);
    float e[5], ssum = 0.f;
    for (int n = 0; n < 5; ++n) { e[n] = expf(sv[n] - m); ssum += e[n]; }
    for (int n = 0; n < 5; ++n) {
      float v = e[n] / ssum;
      sv[n] = v;
      sout[b * 5 + n] = v;
    }
  }
  __syncthreads();
  float cacc = bc1[t];
  for (int n = 0; n < 5; ++n) cacc = fmaf(sv[n], Wc1[t * 5 + n], cacc);
  cl[t] = fmaxf(cacc, 0.0f);
  __syncthreads();
  float c2 = bc2[t];
  for (int k = 0; k < 64; ++k) c2 = fmaf(cl[k], Wc2[t * 64 + k], c2);
  float v = c2 * att[256 + t];
#pragma unroll
  for (int o = 32; o; o >>= 1) v += __shfl_xor(v, o);
  if (t == 0) ec[b] = v;
}

// ---------------- fused softmax(e_tilde) @ Z via MFMA, pipelined ----------------
// 256 threads = 4 waves; 64 i-rows per block, full f=128.
// Double-buffered Zk staging; tile t+1 prefetched during tile t; barriers are
// lgkm-only so global prefetches stay outstanding across them.
__global__ __launch_bounds__(256) void k_main(const uint4* __restrict__ Zk,
    const float* __restrict__ logA, const float* __restrict__ ei,
    const float* __restrict__ ej, const float* __restrict__ ec,
    const float* __restrict__ lam, float* __restrict__ hout) {
  __shared__ float4 ejs4[256];
  __shared__ float mrow[64], sinv[64];
  __shared__ __align__(16) short zt[2][8192];  // 2 x (16 regions x 64 lanes x 8 bf16)

  int tid = threadIdx.x;
  int b = blockIdx.y, i0 = blockIdx.x * 64;
  const float* ejs = (const float*)ejs4;

  const float4* ej4 = (const float4*)(ej + b * 1024);
  ejs4[tid] = ej4[tid];
  float lamv = lam[0];
  float ecb = ec[b];

  int wave = tid >> 6, lane = tid & 63;
  int lg = lane >> 4, ln = lane & 15;
  const uint4* ZkB = Zk + (size_t)b * 128 * 128;

  // prefetch tile 0 (latency hides under pass 1)
  uint4 sv[4];
#pragma unroll
  for (int q = 0; q < 4; ++q) {
    int rgi = wave * 4 + q;
    int ks = rgi >> 3, fb = rgi & 7;
    sv[q] = ZkB[(size_t)(ks * 4 + lg) * 128 + fb * 16 + ln];
  }
  __syncthreads();   // ejs4 visible

  // ---- pass 1: per-row max & inv-sum (wave w owns rows w*16..+15) ----
  for (int rr = 0; rr < 16; ++rr) {
    int r = wave * 16 + rr;
    float eir = ei[b * 1024 + i0 + r];
    const float* lrow = logA + (size_t)(i0 + r) * 1024;
    float tv[16];
    float m = -1e30f;
#pragma unroll
    for (int k = 0; k < 16; ++k) {
      int j = lane + k * 64;
      float t = eir + ejs[j] + ecb;
      t = t > 0.0f ? t : 0.2f * t;          // leaky_relu(0.2)
      t = fmaf(lamv, lrow[j], t);           // + lam*log(A+eps)
      tv[k] = t; m = fmaxf(m, t);
    }
#pragma unroll
    for (int o = 32; o; o >>= 1) m = fmaxf(m, __shfl_xor(m, o));
    float s = 0.0f;
#pragma unroll
    for (int k = 0; k < 16; ++k) s += expf(tv[k] - m);
#pragma unroll
    for (int o = 32; o; o >>= 1) s += __shfl_xor(s, o);
    if (lane == 0) { mrow[r] = m; sinv[r] = 1.0f / s; }
  }
  __syncthreads();

  // ---- pass 2 setup ----
  int i_gl = i0 + wave * 16 + ln;            // this lane's A-row
  float eir2 = ei[b * 1024 + i_gl];
  float mr = mrow[wave * 16 + ln];
  float si = sinv[wave * 16 + ln];
  const float4* lrow4 = (const float4*)(logA + (size_t)i_gl * 1024);

  f32x4 acc[8];
#pragma unroll
  for (int q = 0; q < 8; ++q) { f32x4 z = {0.f, 0.f, 0.f, 0.f}; acc[q] = z; }

  // ---- pipelined j-tile loop ----
  for (int jt = 0; jt < 16; ++jt) {
    int cur = jt & 1;
    int j0 = jt * 64;
    LGKM_BARRIER();    // readers of zt[cur] (iter jt-2) are drained; vmcnt NOT drained
    // commit prefetched tile jt to LDS (compiler inserts precise vmcnt wait)
#pragma unroll
    for (int q = 0; q < 4; ++q)
      *(uint4*)(&zt[cur][(wave * 4 + q) * 512 + lane * 8]) = sv[q];
    // prefetch tile jt+1
    if (jt < 15) {
#pragma unroll
      for (int q = 0; q < 4; ++q) {
        int rgi = wave * 4 + q;
        int ks = rgi >> 3, fb = rgi & 7;
        int jgrp = (jt + 1) * 8 + ks * 4 + lg;
        sv[q] = ZkB[(size_t)jgrp * 128 + fb * 16 + ln];
      }
    }
    // build P fragments for tile jt (fp32, identical formula to pass 1)
    bf16x8 pf[2];
#pragma unroll
    for (int ks = 0; ks < 2; ++ks) {
      int jb = (j0 + ks * 32 + lg * 8) >> 2;
      float4 la0 = lrow4[jb], la1 = lrow4[jb + 1];
      float4 e0 = ejs4[jb], e1 = ejs4[jb + 1];
      float eq[8] = {e0.x, e0.y, e0.z, e0.w, e1.x, e1.y, e1.z, e1.w};
      float lq[8] = {la0.x, la0.y, la0.z, la0.w, la1.x, la1.y, la1.z, la1.w};
      unsigned pw[4];
#pragma unroll
      for (int q = 0; q < 4; ++q) {
        float t0 = eir2 + eq[2 * q] + ecb;     t0 = t0 > 0.f ? t0 : 0.2f * t0;
        float t1 = eir2 + eq[2 * q + 1] + ecb; t1 = t1 > 0.f ? t1 : 0.2f * t1;
        t0 = fmaf(lamv, lq[2 * q], t0);
        t1 = fmaf(lamv, lq[2 * q + 1], t1);
        float p0 = expf(t0 - mr) * si;
        float p1 = expf(t1 - mr) * si;
        pw[q] = f2bf(p0) | (f2bf(p1) << 16);
      }
      union { uint4 u; bf16x8 v; } cvt;
      cvt.u = make_uint4(pw[0], pw[1], pw[2], pw[3]);
      pf[ks] = cvt.v;
    }
    LGKM_BARRIER();    // zt[cur] writes visible to all waves
#pragma unroll
    for (int ks = 0; ks < 2; ++ks) {
#pragma unroll
      for (int fb = 0; fb < 8; ++fb) {
        bf16x8 bz = *(const bf16x8*)(&zt[cur][(ks * 8 + fb) * 512 + lane * 8]);
        acc[fb] = __builtin_amdgcn_mfma_f32_16x16x32_bf16(pf[ks], bz, acc[fb], 0, 0, 0);
      }
    }
  }

  // epilogue: D[row = lg*4+r][col = ln] per 16x16 fragment fb
  float* hb = hout + ((size_t)b * 1024 + i0 + wave * 16 + lg * 4) * 128 + ln;
#pragma unroll
  for (int fb = 0; fb < 8; ++fb) {
#pragma unroll
    for (int r = 0; r < 4; ++r)
      hb[(size_t)r * 128 + fb * 16] = acc[fb][r];
  }
}

extern "C" void kernel_launch(void* const* d_in, const int* in_sizes, int n_in,
                              void* d_out, int out_size, void* d_ws, size_t ws_size,
                              hipStream_t stream) {
  const float* x     = (const float*)d_in[0];
  const float* Ainit = (const float*)d_in[1];
  const float* Wproj = (const float*)d_in[2];
  const float* bproj = (const float*)d_in[3];
  const float* Ws1   = (const float*)d_in[4];
  const float* bs1   = (const float*)d_in[5];
  const float* Ws2   = (const float*)d_in[6];
  const float* bs2   = (const float*)d_in[7];
  const float* Wc1   = (const float*)d_in[8];
  const float* bc1   = (const float*)d_in[9];
  const float* Wc2   = (const float*)d_in[10];
  const float* bc2   = (const float*)d_in[11];
  const float* att   = (const float*)d_in[12];
  const float* lam   = (const float*)d_in[13];

  float* ws    = (float*)d_ws;
  float* logA  = ws + LOGA_OFF;
  float* xred  = ws + XRED_OFF;
  float* xglob = ws + XGLOB_OFF;
  float* Zb    = ws + Z_OFF;
  float* ei    = ws + EI_OFF;
  float* ej    = ws + EJ_OFF;
  float* ec    = ws + EC_OFF;
  uint4* Zk    = (uint4*)(ws + ZK_OFF);

  float* hout = (float*)d_out;                  // (32,1024,128)
  float* sout = hout + (size_t)32 * 1024 * 128; // (32,5)

  hipLaunchKernelGGL(k_logA,  dim3(1024),    dim3(256), 0, stream, Ainit, logA);
  hipLaunchKernelGGL(k_xred,  dim3(2048),    dim3(256), 0, stream,
                     (const float4*)x, (float4*)xred);
  hipLaunchKernelGGL(k_xglob, dim3(32),      dim3(256), 0, stream, xred, xglob);
  hipLaunchKernelGGL(k_Z,     dim3(1024),    dim3(256), 0, stream,
                     (const float4*)xred, Wproj, bproj, Zb, Zk);
  hipLaunchKernelGGL(k_e,     dim3(8192),    dim3(256), 0, stream, Zb, att, ei, ej);
  hipLaunchKernelGGL(k_small, dim3(32),      dim3(64),  0, stream, xglob,
                     Ws1, bs1, Ws2, bs2, Wc1, bc1, Wc2, bc2, att, sout, ec);
  hipLaunchKernelGGL(k_main,  dim3(16, 32),  dim3(256), 0, stream,
                     Zk, logA, ei, ej, ec, lam, hout);
}

// Round 7
// 239.208 us; speedup vs baseline: 2.1669x; 1.4153x over previous
//
#include <hip/hip_runtime.h>
#include <cstddef>
#include <math.h>

// Problem dims
// B=32, C=1024, T=64, D=64, F_OUT=128, S_DIM=64, N_STG=5, H_MLP=64

typedef __attribute__((ext_vector_type(8))) short bf16x8;
typedef __attribute__((ext_vector_type(4))) float f32x4;

__device__ inline unsigned f2bf(float f) {
  unsigned u = __float_as_uint(f);
  return (u + 0x7FFFu + ((u >> 16) & 1u)) >> 16;   // RTN-even
}

// workspace layout (float offsets)
#define LOGA_OFF  0u          // lam*log(A+eps): 1024*1024 = 1048576
#define XRED_OFF  1048576u    // 32*1024*64 = 2097152
#define EI_OFF    3145728u    // 32768
#define EJ_OFF    3178496u    // 32768
#define EC_OFF    3211264u    // 32
#define ZK_OFF    3211296u    // bf16 k-major Z: 2097152 floats worth

// ---------------- llogA = lam * log(A + 1e-8) ----------------
__global__ __launch_bounds__(256) void k_logA(const float* __restrict__ A,
                                              const float* __restrict__ lam,
                                              float* __restrict__ out) {
  float l = lam[0];
  int base = blockIdx.x * 1024 + threadIdx.x;
#pragma unroll
  for (int k = 0; k < 4; ++k)
    out[base + k * 256] = l * __logf(A[base + k * 256] + 1e-8f);
}

// ---------------- x_red = mean over T (pure stream, no LDS) ----------------
__global__ __launch_bounds__(256) void k_xred(const float4* __restrict__ X4,
                                              float4* __restrict__ XR4) {
  int tid = threadIdx.x;
  int cl = tid >> 4, dq = tid & 15;
  size_t row = (size_t)blockIdx.x * 16 + cl;     // b*1024 + c
  const float4* base = X4 + row * 1024 + dq;
  float4 a0 = make_float4(0.f, 0.f, 0.f, 0.f);
  float4 a1 = a0, a2 = a0, a3 = a0;
#pragma unroll
  for (int t = 0; t < 64; t += 4) {
    float4 v0 = base[(t + 0) * 16];
    float4 v1 = base[(t + 1) * 16];
    float4 v2 = base[(t + 2) * 16];
    float4 v3 = base[(t + 3) * 16];
    a0.x += v0.x; a0.y += v0.y; a0.z += v0.z; a0.w += v0.w;
    a1.x += v1.x; a1.y += v1.y; a1.z += v1.z; a1.w += v1.w;
    a2.x += v2.x; a2.y += v2.y; a2.z += v2.z; a2.w += v2.w;
    a3.x += v3.x; a3.y += v3.y; a3.z += v3.z; a3.w += v3.w;
  }
  const float inv = 1.0f / 64.0f;
  float4 s;
  s.x = ((a0.x + a1.x) + (a2.x + a3.x)) * inv;
  s.y = ((a0.y + a1.y) + (a2.y + a3.y)) * inv;
  s.z = ((a0.z + a1.z) + (a2.z + a3.z)) * inv;
  s.w = ((a0.w + a1.w) + (a2.w + a3.w)) * inv;
  XR4[row * 16 + dq] = s;
}

// ---------------- Z-project + Zk(bf16) + ei/ej (fused) ----------------
// 32 rows per block. After the GEMV, the fp32 Z tile is staged in LDS
// (reusing the W buffer) to reduce ei = Z@a_i, ej = Z@a_j in-block.
// No fp32 Z ever goes to HBM.
__global__ __launch_bounds__(256) void k_Z(const float4* __restrict__ XR4,
                                           const float* __restrict__ W,
                                           const float* __restrict__ bproj,
                                           const float* __restrict__ att,
                                           uint4* __restrict__ Zk,
                                           float* __restrict__ ei,
                                           float* __restrict__ ej) {
  __shared__ float Wl[64 * 129];     // also reused as Zl[32][130]
  __shared__ float4 xr4[32 * 16];
  int tid = threadIdx.x;
  int rb = blockIdx.x * 32;
#pragma unroll
  for (int k = 0; k < 32; ++k) {
    int g = k * 256 + tid;           // g = f*64 + d
    Wl[(g & 63) * 129 + (g >> 6)] = W[g];
  }
#pragma unroll
  for (int k = 0; k < 2; ++k)
    xr4[k * 256 + tid] = XR4[(size_t)rb * 16 + k * 256 + tid];
  __syncthreads();

  int f = tid & 127, rg = tid >> 7;
  float wreg[64];
#pragma unroll
  for (int d = 0; d < 64; ++d) wreg[d] = Wl[d * 129 + f];
  float bias = bproj[f];
  float acc[16];
#pragma unroll
  for (int r = 0; r < 16; ++r) acc[r] = bias;
#pragma unroll
  for (int r = 0; r < 16; ++r) {
    int row = rg * 16 + r;
#pragma unroll
    for (int dq = 0; dq < 16; ++dq) {
      float4 xv = xr4[row * 16 + dq];
      acc[r] = fmaf(wreg[dq * 4 + 0], xv.x, acc[r]);
      acc[r] = fmaf(wreg[dq * 4 + 1], xv.y, acc[r]);
      acc[r] = fmaf(wreg[dq * 4 + 2], xv.z, acc[r]);
      acc[r] = fmaf(wreg[dq * 4 + 3], xv.w, acc[r]);
    }
  }
  // bf16 k-major chunks: Zk[b][c/8][f][c&7]
  int b = rb >> 10;
  int cbase = (rb & 1023) + rg * 16;
#pragma unroll
  for (int k2 = 0; k2 < 2; ++k2) {
    unsigned w0 = f2bf(acc[k2 * 8 + 0]) | (f2bf(acc[k2 * 8 + 1]) << 16);
    unsigned w1 = f2bf(acc[k2 * 8 + 2]) | (f2bf(acc[k2 * 8 + 3]) << 16);
    unsigned w2 = f2bf(acc[k2 * 8 + 4]) | (f2bf(acc[k2 * 8 + 5]) << 16);
    unsigned w3 = f2bf(acc[k2 * 8 + 6]) | (f2bf(acc[k2 * 8 + 7]) << 16);
    size_t chunk = ((size_t)b * 128 + ((cbase >> 3) + k2)) * 128 + f;
    Zk[chunk] = make_uint4(w0, w1, w2, w3);
  }
  // ---- ei/ej tail: stage Z tile into LDS (reuse Wl), reduce ----
  __syncthreads();                   // all Wl/xr4 reads done
  float* Zl = Wl;                    // [32][130]
#pragma unroll
  for (int r = 0; r < 16; ++r)
    Zl[(rg * 16 + r) * 130 + f] = acc[r];
  __syncthreads();
  int row = tid >> 3, g = tid & 7;   // 32 rows x 8 groups of 16 f
  float si = 0.f, sj = 0.f;
#pragma unroll
  for (int u = 0; u < 16; ++u) {
    float z = Zl[row * 130 + g * 16 + u];
    si = fmaf(z, att[g * 16 + u], si);
    sj = fmaf(z, att[128 + g * 16 + u], sj);
  }
  si += __shfl_xor(si, 1); sj += __shfl_xor(sj, 1);
  si += __shfl_xor(si, 2); sj += __shfl_xor(sj, 2);
  si += __shfl_xor(si, 4); sj += __shfl_xor(sj, 4);
  if (g == 0) { ei[rb + row] = si; ej[rb + row] = sj; }
}

// ---------------- x_glob + s/c/e_c chain (fused) ----------------
__global__ __launch_bounds__(256) void k_gs(const float* __restrict__ XR,
    const float* __restrict__ Ws1, const float* __restrict__ bs1,
    const float* __restrict__ Ws2, const float* __restrict__ bs2,
    const float* __restrict__ Wc1, const float* __restrict__ bc1,
    const float* __restrict__ Wc2, const float* __restrict__ bc2,
    const float* __restrict__ att, float* __restrict__ sout,
    float* __restrict__ ec) {
  __shared__ float part[256];
  __shared__ float xg[64], hid[64], sv[5], cl[64];
  int b = blockIdx.x, tid = threadIdx.x;
  int d = tid & 63, cq = tid >> 6;
  float a = 0.f;
  for (int c = cq; c < 1024; c += 4)
    a += XR[((size_t)b * 1024 + c) * 64 + d];
  part[tid] = a;
  __syncthreads();
  if (tid < 64)
    xg[tid] = (part[tid] + part[64 + tid] + part[128 + tid] + part[192 + tid])
              * (1.0f / 1024.0f);
  __syncthreads();
  if (tid < 64) {
    float h = bs1[tid];
    for (int d2 = 0; d2 < 64; ++d2) h = fmaf(xg[d2], Ws1[tid * 64 + d2], h);
    hid[tid] = fmaxf(h, 0.0f);
  }
  __syncthreads();
  if (tid < 5) {
    float l = bs2[tid];
    for (int k = 0; k < 64; ++k) l = fmaf(hid[k], Ws2[tid * 64 + k], l);
    sv[tid] = l;
  }
  __syncthreads();
  if (tid == 0) {
    float m = sv[0];
    for (int n = 1; n < 5; ++n) m = fmaxf(m, sv[n]);
    float e[5], ssum = 0.f;
    for (int n = 0; n < 5; ++n) { e[n] = expf(sv[n] - m); ssum += e[n]; }
    for (int n = 0; n < 5; ++n) {
      float v = e[n] / ssum;
      sv[n] = v;
      sout[b * 5 + n] = v;
    }
  }
  __syncthreads();
  if (tid < 64) {
    float cacc = bc1[tid];
    for (int n = 0; n < 5; ++n) cacc = fmaf(sv[n], Wc1[tid * 5 + n], cacc);
    cl[tid] = fmaxf(cacc, 0.0f);
  }
  __syncthreads();
  if (tid < 64) {
    float c2 = bc2[tid];
    for (int k = 0; k < 64; ++k) c2 = fmaf(cl[k], Wc2[tid * 64 + k], c2);
    float v = c2 * att[256 + tid];
#pragma unroll
    for (int o = 32; o; o >>= 1) v += __shfl_xor(v, o);
    if (tid == 0) ec[b] = v;
  }
}

// ---------------- fused online-softmax(e_tilde) @ Z via MFMA ----------------
// One independent 64-lane wave per (b, 16-row group). No LDS, no barriers.
// B-fragments read straight from L2-resident Zk. Flash-style running (m,s);
// normalization applied in the epilogue.
// A-frag: lane(ln,lg) holds P[row=ln][k=lg*8+u]; B-frag: B[k=lg*8+u][n=ln].
// C/D: D[m=lg*4+r][n=ln] (verified mapping, unchanged from passing R5 kernel).
__global__ __launch_bounds__(64) void k_main(const uint4* __restrict__ Zk,
    const float* __restrict__ llogA, const float* __restrict__ ei,
    const float* __restrict__ ej, const float* __restrict__ ec,
    float* __restrict__ hout) {
  int bid = blockIdx.x;
  // XCD-bijective decode: xcd = bid&7 owns batches 4*xcd..4*xcd+3
  int b = ((bid & 7) << 2) | ((bid >> 3) & 3);
  int rowgrp = bid >> 5;               // 0..63
  int i0 = rowgrp * 16;
  int lane = threadIdx.x;
  int lg = lane >> 4, ln = lane & 15;

  int i_gl = i0 + ln;
  float eir = ei[b * 1024 + i_gl];
  float ecb = ec[b];
  const float4* lrow4 = (const float4*)(llogA + (size_t)i_gl * 1024);
  const float4* ejr4  = (const float4*)(ej + b * 1024);
  const uint4*  ZkB   = Zk + (size_t)b * 128 * 128;

  float m_run = -1e30f, s_run = 0.0f;
  f32x4 acc[8];
#pragma unroll
  for (int q = 0; q < 8; ++q) { f32x4 z = {0.f, 0.f, 0.f, 0.f}; acc[q] = z; }

  for (int jt = 0; jt < 16; ++jt) {
    int j0 = jt * 64;
    // B-fragment loads: 16 x b128 from L2 (no staging)
    uint4 bz[2][8];
#pragma unroll
    for (int ks = 0; ks < 2; ++ks)
#pragma unroll
      for (int fb = 0; fb < 8; ++fb)
        bz[ks][fb] = ZkB[(size_t)((j0 >> 3) + ks * 4 + lg) * 128 + fb * 16 + ln];
    // e_tilde for this lane's 16 j's
    float tv[16];
    float tm = -1e30f;
#pragma unroll
    for (int ks = 0; ks < 2; ++ks) {
      int jb = (j0 + ks * 32 + lg * 8) >> 2;
      float4 e0 = ejr4[jb], e1 = ejr4[jb + 1];
      float4 l0 = lrow4[jb], l1 = lrow4[jb + 1];
      float eq[8] = {e0.x, e0.y, e0.z, e0.w, e1.x, e1.y, e1.z, e1.w};
      float lq[8] = {l0.x, l0.y, l0.z, l0.w, l1.x, l1.y, l1.z, l1.w};
#pragma unroll
      for (int u = 0; u < 8; ++u) {
        float t = eir + eq[u] + ecb;
        t = t > 0.0f ? t : 0.2f * t;          // leaky_relu(0.2)
        t += lq[u];                            // + lam*log(A+eps)
        tv[ks * 8 + u] = t;
        tm = fmaxf(tm, t);
      }
    }
    // row max across the 4 lg-lanes sharing this row
    tm = fmaxf(tm, __shfl_xor(tm, 16));
    tm = fmaxf(tm, __shfl_xor(tm, 32));
    float newm = fmaxf(m_run, tm);
    float scale = __expf(m_run - newm);
    float ts = 0.0f;
    unsigned pw[8];
#pragma unroll
    for (int q = 0; q < 8; ++q) {
      float p0 = __expf(tv[2 * q] - newm);
      float p1 = __expf(tv[2 * q + 1] - newm);
      ts += p0 + p1;
      pw[q] = f2bf(p0) | (f2bf(p1) << 16);
    }
    ts += __shfl_xor(ts, 16);
    ts += __shfl_xor(ts, 32);
    s_run = s_run * scale + ts;
    m_run = newm;
#pragma unroll
    for (int q = 0; q < 8; ++q) acc[q] *= scale;
    union { unsigned u[4]; bf16x8 v; } c0, c1;
#pragma unroll
    for (int q = 0; q < 4; ++q) { c0.u[q] = pw[q]; c1.u[q] = pw[4 + q]; }
#pragma unroll
    for (int fb = 0; fb < 8; ++fb)
      acc[fb] = __builtin_amdgcn_mfma_f32_16x16x32_bf16(c0.v, *(bf16x8*)&bz[0][fb], acc[fb], 0, 0, 0);
#pragma unroll
    for (int fb = 0; fb < 8; ++fb)
      acc[fb] = __builtin_amdgcn_mfma_f32_16x16x32_bf16(c1.v, *(bf16x8*)&bz[1][fb], acc[fb], 0, 0, 0);
  }

  // epilogue: normalize by the D-row's 1/s (fetched via shfl), write out
  float invs = 1.0f / s_run;
  float inv_m[4];
#pragma unroll
  for (int r = 0; r < 4; ++r) inv_m[r] = __shfl(invs, lg * 4 + r);
  float* hb = hout + ((size_t)b * 1024 + i0 + lg * 4) * 128 + ln;
#pragma unroll
  for (int fb = 0; fb < 8; ++fb) {
#pragma unroll
    for (int r = 0; r < 4; ++r)
      hb[(size_t)r * 128 + fb * 16] = acc[fb][r] * inv_m[r];
  }
}

extern "C" void kernel_launch(void* const* d_in, const int* in_sizes, int n_in,
                              void* d_out, int out_size, void* d_ws, size_t ws_size,
                              hipStream_t stream) {
  const float* x     = (const float*)d_in[0];
  const float* Ainit = (const float*)d_in[1];
  const float* Wproj = (const float*)d_in[2];
  const float* bproj = (const float*)d_in[3];
  const float* Ws1   = (const float*)d_in[4];
  const float* bs1   = (const float*)d_in[5];
  const float* Ws2   = (const float*)d_in[6];
  const float* bs2   = (const float*)d_in[7];
  const float* Wc1   = (const float*)d_in[8];
  const float* bc1   = (const float*)d_in[9];
  const float* Wc2   = (const float*)d_in[10];
  const float* bc2   = (const float*)d_in[11];
  const float* att   = (const float*)d_in[12];
  const float* lam   = (const float*)d_in[13];

  float* ws    = (float*)d_ws;
  float* llogA = ws + LOGA_OFF;
  float* xred  = ws + XRED_OFF;
  float* ei    = ws + EI_OFF;
  float* ej    = ws + EJ_OFF;
  float* ec    = ws + EC_OFF;
  uint4* Zk    = (uint4*)(ws + ZK_OFF);

  float* hout = (float*)d_out;                  // (32,1024,128)
  float* sout = hout + (size_t)32 * 1024 * 128; // (32,5)

  hipLaunchKernelGGL(k_logA, dim3(1024), dim3(256), 0, stream, Ainit, lam, llogA);
  hipLaunchKernelGGL(k_xred, dim3(2048), dim3(256), 0, stream,
                     (const float4*)x, (float4*)xred);
  hipLaunchKernelGGL(k_Z,    dim3(1024), dim3(256), 0, stream,
                     (const float4*)xred, Wproj, bproj, att, Zk, ei, ej);
  hipLaunchKernelGGL(k_gs,   dim3(32),   dim3(256), 0, stream, xred,
                     Ws1, bs1, Ws2, bs2, Wc1, bc1, Wc2, bc2, att, sout, ec);
  hipLaunchKernelGGL(k_main, dim3(2048), dim3(64),  0, stream,
                     Zk, llogA, ei, ej, ec, hout);
}

// Round 8
// 180.550 us; speedup vs baseline: 2.8708x; 1.3249x over previous
//
#include <hip/hip_runtime.h>
#include <cstddef>
#include <math.h>

// Problem dims
// B=32, C=1024, T=64, D=64, F_OUT=128, S_DIM=64, N_STG=5, H_MLP=64

typedef __attribute__((ext_vector_type(8))) short bf16x8;
typedef __attribute__((ext_vector_type(4))) float f32x4;

__device__ inline unsigned f2bf(float f) {
  unsigned u = __float_as_uint(f);
  return (u + 0x7FFFu + ((u >> 16) & 1u)) >> 16;   // RTN-even
}

// workspace layout (float offsets)
#define LOGA_OFF 0u          // lam*log(A+eps): 1048576
#define EI_OFF   1048576u    // 32768
#define EJ_OFF   1081344u    // 32768
#define PXG_OFF  1114112u    // partial x_glob: 1024 blocks x 64 = 65536
#define ZK_OFF   1179648u    // bf16 k-major Z: 2097152 floats worth

// ================= K1: mega-fused producer =================
// blocks 0..1023:  32 C-rows each: stream x (mean over T) -> Z GEMV ->
//                  bf16 Zk (k-major) + ei/ej + partial x_glob
// blocks 1024..2047: llogA = lam*log(A+1e-8)
__global__ __launch_bounds__(256) void k_fuse1(
    const float4* __restrict__ X4, const float* __restrict__ A,
    const float* __restrict__ lam, const float* __restrict__ W,
    const float* __restrict__ bproj, const float* __restrict__ att,
    uint4* __restrict__ Zk, float* __restrict__ ei, float* __restrict__ ej,
    float4* __restrict__ pXG4, float* __restrict__ llogA) {
  int tid = threadIdx.x;
  int bk = blockIdx.x;
  if (bk >= 1024) {
    float l = lam[0];
    int base = (bk - 1024) * 1024 + tid;
#pragma unroll
    for (int k = 0; k < 4; ++k)
      llogA[base + k * 256] = l * __logf(A[base + k * 256] + 1e-8f);
    return;
  }
  __shared__ float Wl[64 * 129];     // W transposed [d][f]; later reused as Zl[32][130]
  __shared__ float4 xr4[32 * 16];    // x_red tile [row][dq]
  int rb = bk * 32;                  // flat row base (b*1024 + c0)

  // stage W transposed (L2-hot after first blocks)
#pragma unroll
  for (int k = 0; k < 32; ++k) {
    int g = k * 256 + tid;           // g = f*64 + d
    Wl[(g & 63) * 129 + (g >> 6)] = W[g];
  }

  // stream x: mean over T for this block's 32 rows.
  // thread (row=tid>>3, g=tid&7): addr = row*1024 + k*8 + g;
  // k even -> (t=k/2, dq=g), k odd -> (t=k/2, dq=g+8).
  {
    int row = tid >> 3, g = tid & 7;
    const float4* xbase = X4 + ((size_t)(rb + row)) * 1024 + g;
    float4 a0 = make_float4(0.f, 0.f, 0.f, 0.f), a1 = a0;
#pragma unroll
    for (int k = 0; k < 128; k += 2) {
      float4 v0 = xbase[k * 8];
      float4 v1 = xbase[k * 8 + 8];
      a0.x += v0.x; a0.y += v0.y; a0.z += v0.z; a0.w += v0.w;
      a1.x += v1.x; a1.y += v1.y; a1.z += v1.z; a1.w += v1.w;
    }
    const float inv = 1.0f / 64.0f;
    a0.x *= inv; a0.y *= inv; a0.z *= inv; a0.w *= inv;
    a1.x *= inv; a1.y *= inv; a1.z *= inv; a1.w *= inv;
    xr4[row * 16 + g] = a0;
    xr4[row * 16 + g + 8] = a1;
  }
  __syncthreads();

  // partial x_glob: sum of this block's 32 xr rows (means over t already)
  if (tid < 16) {
    float4 p = make_float4(0.f, 0.f, 0.f, 0.f);
#pragma unroll
    for (int r = 0; r < 32; ++r) {
      float4 v = xr4[r * 16 + tid];
      p.x += v.x; p.y += v.y; p.z += v.z; p.w += v.w;
    }
    pXG4[bk * 16 + tid] = p;
  }

  // GEMV: Z[row][f] = b[f] + xr[row,:] . W[f,:]
  int f = tid & 127, rg = tid >> 7;
  float wreg[64];
#pragma unroll
  for (int d = 0; d < 64; ++d) wreg[d] = Wl[d * 129 + f];
  float bias = bproj[f];
  float acc[16];
#pragma unroll
  for (int r = 0; r < 16; ++r) acc[r] = bias;
#pragma unroll
  for (int r = 0; r < 16; ++r) {
    int row = rg * 16 + r;
#pragma unroll
    for (int dq = 0; dq < 16; ++dq) {
      float4 xv = xr4[row * 16 + dq];
      acc[r] = fmaf(wreg[dq * 4 + 0], xv.x, acc[r]);
      acc[r] = fmaf(wreg[dq * 4 + 1], xv.y, acc[r]);
      acc[r] = fmaf(wreg[dq * 4 + 2], xv.z, acc[r]);
      acc[r] = fmaf(wreg[dq * 4 + 3], xv.w, acc[r]);
    }
  }
  // bf16 k-major chunks: Zk[b][c/8][f][c&7]
  int b = rb >> 10;
  int cbase = (rb & 1023) + rg * 16;
#pragma unroll
  for (int k2 = 0; k2 < 2; ++k2) {
    unsigned w0 = f2bf(acc[k2 * 8 + 0]) | (f2bf(acc[k2 * 8 + 1]) << 16);
    unsigned w1 = f2bf(acc[k2 * 8 + 2]) | (f2bf(acc[k2 * 8 + 3]) << 16);
    unsigned w2 = f2bf(acc[k2 * 8 + 4]) | (f2bf(acc[k2 * 8 + 5]) << 16);
    unsigned w3 = f2bf(acc[k2 * 8 + 6]) | (f2bf(acc[k2 * 8 + 7]) << 16);
    size_t chunk = ((size_t)b * 128 + ((cbase >> 3) + k2)) * 128 + f;
    Zk[chunk] = make_uint4(w0, w1, w2, w3);
  }
  // ei/ej tail: stage fp32 Z tile into LDS (reuse Wl), reduce
  __syncthreads();                   // all Wl/xr4 reads done
  float* Zl = Wl;                    // [32][130]
#pragma unroll
  for (int r = 0; r < 16; ++r)
    Zl[(rg * 16 + r) * 130 + f] = acc[r];
  __syncthreads();
  int row = tid >> 3, g = tid & 7;   // 32 rows x 8 groups of 16 f
  float si = 0.f, sj = 0.f;
#pragma unroll
  for (int u = 0; u < 16; ++u) {
    float z = Zl[row * 130 + g * 16 + u];
    si = fmaf(z, att[g * 16 + u], si);
    sj = fmaf(z, att[128 + g * 16 + u], sj);
  }
  si += __shfl_xor(si, 1); sj += __shfl_xor(sj, 1);
  si += __shfl_xor(si, 2); sj += __shfl_xor(sj, 2);
  si += __shfl_xor(si, 4); sj += __shfl_xor(sj, 4);
  if (g == 0) { ei[rb + row] = si; ej[rb + row] = sj; }
}

// ================= K2: flash softmax @ Z via MFMA =================
// One independent wave per (b, 16-row group). No LDS, no barriers.
// Pre-phase: redundant per-wave s/c/ec MLP chain from partial x_glob
// (bitwise identical across waves of a batch -> deterministic); rowgrp-0
// blocks write the s output.
__global__ __launch_bounds__(64) void k_main(const uint4* __restrict__ Zk,
    const float* __restrict__ llogA, const float* __restrict__ ei,
    const float* __restrict__ ej, const float* __restrict__ pXG,
    const float* __restrict__ Ws1, const float* __restrict__ bs1,
    const float* __restrict__ Ws2, const float* __restrict__ bs2,
    const float* __restrict__ Wc1, const float* __restrict__ bc1,
    const float* __restrict__ Wc2, const float* __restrict__ bc2,
    const float* __restrict__ att,
    float* __restrict__ hout, float* __restrict__ sout) {
  int bid = blockIdx.x;
  // XCD-bijective decode: all 64 row-groups of a batch land on one XCD
  int b = ((bid & 7) << 2) | ((bid >> 3) & 3);
  int rowgrp = bid >> 5;               // 0..63
  int i0 = rowgrp * 16;
  int lane = threadIdx.x;
  int lg = lane >> 4, ln = lane & 15;

  // ---- pre-phase: x_glob -> s -> c -> ec (shfl-based, wave-local) ----
  float ecb;
  {
    float xg = 0.f;
    const float* pb = pXG + (size_t)b * 32 * 64;
#pragma unroll 8
    for (int p = 0; p < 32; ++p) xg += pb[p * 64 + lane];
    xg *= (1.0f / 1024.0f);
    // hid[t] = relu(bs1 + xg . Ws1[t,:])
    const float* w1 = Ws1 + lane * 64;
    float h = bs1[lane];
#pragma unroll 16
    for (int d = 0; d < 64; ++d) h = fmaf(__shfl(xg, d), w1[d], h);
    h = fmaxf(h, 0.f);
    // logits (lanes 0..4)
    int ln5 = lane < 5 ? lane : 4;
    const float* w2 = Ws2 + ln5 * 64;
    float l = bs2[ln5];
#pragma unroll 16
    for (int k = 0; k < 64; ++k) l = fmaf(__shfl(h, k), w2[k], l);
    float s0 = __shfl(l, 0), s1 = __shfl(l, 1), s2 = __shfl(l, 2),
          s3 = __shfl(l, 3), s4 = __shfl(l, 4);
    float m = fmaxf(fmaxf(fmaxf(s0, s1), fmaxf(s2, s3)), s4);
    float e0 = __expf(s0 - m), e1 = __expf(s1 - m), e2 = __expf(s2 - m),
          e3 = __expf(s3 - m), e4 = __expf(s4 - m);
    float inv = 1.0f / (e0 + e1 + e2 + e3 + e4);
    s0 = e0 * inv; s1 = e1 * inv; s2 = e2 * inv; s3 = e3 * inv; s4 = e4 * inv;
    if (rowgrp == 0 && lane == 0) {
      sout[b * 5 + 0] = s0; sout[b * 5 + 1] = s1; sout[b * 5 + 2] = s2;
      sout[b * 5 + 3] = s3; sout[b * 5 + 4] = s4;
    }
    // c1 (relu), c2, ec = (c2 * a_c) summed
    const float* wc1 = Wc1 + lane * 5;
    float cv = bc1[lane];
    cv = fmaf(s0, wc1[0], cv); cv = fmaf(s1, wc1[1], cv);
    cv = fmaf(s2, wc1[2], cv); cv = fmaf(s3, wc1[3], cv);
    cv = fmaf(s4, wc1[4], cv);
    cv = fmaxf(cv, 0.f);
    const float* wc2 = Wc2 + lane * 64;
    float c2 = bc2[lane];
#pragma unroll 16
    for (int k = 0; k < 64; ++k) c2 = fmaf(__shfl(cv, k), wc2[k], c2);
    float v = c2 * att[256 + lane];
#pragma unroll
    for (int o = 32; o; o >>= 1) v += __shfl_xor(v, o);
    ecb = v;                         // xor-butterfly: all lanes hold the sum
  }

  // ---- flash loop ----
  int i_gl = i0 + ln;
  float eir = ei[b * 1024 + i_gl];
  const float4* lrow4 = (const float4*)(llogA + (size_t)i_gl * 1024);
  const float4* ejr4  = (const float4*)(ej + b * 1024);
  const uint4*  ZkB   = Zk + (size_t)b * 128 * 128;

  float m_run = -1e30f, s_run = 0.0f;
  f32x4 acc[8];
#pragma unroll
  for (int q = 0; q < 8; ++q) { f32x4 z = {0.f, 0.f, 0.f, 0.f}; acc[q] = z; }

  for (int jt = 0; jt < 16; ++jt) {
    int j0 = jt * 64;
    uint4 bz[2][8];
#pragma unroll
    for (int ks = 0; ks < 2; ++ks)
#pragma unroll
      for (int fb = 0; fb < 8; ++fb)
        bz[ks][fb] = ZkB[(size_t)((j0 >> 3) + ks * 4 + lg) * 128 + fb * 16 + ln];
    float tv[16];
    float tm = -1e30f;
#pragma unroll
    for (int ks = 0; ks < 2; ++ks) {
      int jb = (j0 + ks * 32 + lg * 8) >> 2;
      float4 e0 = ejr4[jb], e1 = ejr4[jb + 1];
      float4 l0 = lrow4[jb], l1 = lrow4[jb + 1];
      float eq[8] = {e0.x, e0.y, e0.z, e0.w, e1.x, e1.y, e1.z, e1.w};
      float lq[8] = {l0.x, l0.y, l0.z, l0.w, l1.x, l1.y, l1.z, l1.w};
#pragma unroll
      for (int u = 0; u < 8; ++u) {
        float t = eir + eq[u] + ecb;
        t = t > 0.0f ? t : 0.2f * t;          // leaky_relu(0.2)
        t += lq[u];                            // + lam*log(A+eps)
        tv[ks * 8 + u] = t;
        tm = fmaxf(tm, t);
      }
    }
    tm = fmaxf(tm, __shfl_xor(tm, 16));
    tm = fmaxf(tm, __shfl_xor(tm, 32));
    float newm = fmaxf(m_run, tm);
    float scale = __expf(m_run - newm);
    float ts = 0.0f;
    unsigned pw[8];
#pragma unroll
    for (int q = 0; q < 8; ++q) {
      float p0 = __expf(tv[2 * q] - newm);
      float p1 = __expf(tv[2 * q + 1] - newm);
      ts += p0 + p1;
      pw[q] = f2bf(p0) | (f2bf(p1) << 16);
    }
    ts += __shfl_xor(ts, 16);
    ts += __shfl_xor(ts, 32);
    s_run = s_run * scale + ts;
    m_run = newm;
#pragma unroll
    for (int q = 0; q < 8; ++q) acc[q] *= scale;
    union { unsigned u[4]; bf16x8 v; } c0, c1;
#pragma unroll
    for (int q = 0; q < 4; ++q) { c0.u[q] = pw[q]; c1.u[q] = pw[4 + q]; }
#pragma unroll
    for (int fb = 0; fb < 8; ++fb)
      acc[fb] = __builtin_amdgcn_mfma_f32_16x16x32_bf16(c0.v, *(bf16x8*)&bz[0][fb], acc[fb], 0, 0, 0);
#pragma unroll
    for (int fb = 0; fb < 8; ++fb)
      acc[fb] = __builtin_amdgcn_mfma_f32_16x16x32_bf16(c1.v, *(bf16x8*)&bz[1][fb], acc[fb], 0, 0, 0);
  }

  // epilogue: normalize by D-row 1/s, write out
  float invs = 1.0f / s_run;
  float inv_m[4];
#pragma unroll
  for (int r = 0; r < 4; ++r) inv_m[r] = __shfl(invs, lg * 4 + r);
  float* hb = hout + ((size_t)b * 1024 + i0 + lg * 4) * 128 + ln;
#pragma unroll
  for (int fb = 0; fb < 8; ++fb) {
#pragma unroll
    for (int r = 0; r < 4; ++r)
      hb[(size_t)r * 128 + fb * 16] = acc[fb][r] * inv_m[r];
  }
}

extern "C" void kernel_launch(void* const* d_in, const int* in_sizes, int n_in,
                              void* d_out, int out_size, void* d_ws, size_t ws_size,
                              hipStream_t stream) {
  const float* x     = (const float*)d_in[0];
  const float* Ainit = (const float*)d_in[1];
  const float* Wproj = (const float*)d_in[2];
  const float* bproj = (const float*)d_in[3];
  const float* Ws1   = (const float*)d_in[4];
  const float* bs1   = (const float*)d_in[5];
  const float* Ws2   = (const float*)d_in[6];
  const float* bs2   = (const float*)d_in[7];
  const float* Wc1   = (const float*)d_in[8];
  const float* bc1   = (const float*)d_in[9];
  const float* Wc2   = (const float*)d_in[10];
  const float* bc2   = (const float*)d_in[11];
  const float* att   = (const float*)d_in[12];
  const float* lam   = (const float*)d_in[13];

  float* ws    = (float*)d_ws;
  float* llogA = ws + LOGA_OFF;
  float* ei    = ws + EI_OFF;
  float* ej    = ws + EJ_OFF;
  float* pXG   = ws + PXG_OFF;
  uint4* Zk    = (uint4*)(ws + ZK_OFF);

  float* hout = (float*)d_out;                  // (32,1024,128)
  float* sout = hout + (size_t)32 * 1024 * 128; // (32,5)

  hipLaunchKernelGGL(k_fuse1, dim3(2048), dim3(256), 0, stream,
                     (const float4*)x, Ainit, lam, Wproj, bproj, att,
                     Zk, ei, ej, (float4*)pXG, llogA);
  hipLaunchKernelGGL(k_main,  dim3(2048), dim3(64),  0, stream,
                     Zk, llogA, ei, ej, pXG,
                     Ws1, bs1, Ws2, bs2, Wc1, bc1, Wc2, bc2, att,
                     hout, sout);
}